// Round 5
// baseline (1952.126 us; speedup 1.0000x reference)
//
#include <hip/hip_runtime.h>

// ---------------------------------------------------------------------------
// SimplicialAttentionTransformer: 3 streams x (embed-add, 2x[QKV gemm,
// edge scores, GLOBAL softmax over edges, CSR segment-sum, proj gemm, LN],
// head gemm). bf16 MFMA GEMMs: A double-buffered via global_load_lds,
// B (weights, L2-resident) loaded direct global->VGPR, 2-phase pipeline,
// swapped-operand MFMA so each lane owns 4 consecutive output columns.
// ---------------------------------------------------------------------------

typedef __attribute__((ext_vector_type(8))) __bf16 bf16x8;
typedef __attribute__((ext_vector_type(4))) float f32x4;
typedef __attribute__((ext_vector_type(8))) unsigned short ushort8v;
typedef __attribute__((ext_vector_type(4))) unsigned short ushort4v;

__device__ __forceinline__ float b2f(unsigned short u) {
  union { unsigned u; float f; } x; x.u = (unsigned)u << 16; return x.f;
}
__device__ __forceinline__ unsigned short f2b(float f) {
  union { float f; unsigned u; } x; x.f = f;
  unsigned r = x.u + 0x7fffu + ((x.u >> 16) & 1u);   // RNE
  return (unsigned short)(r >> 16);
}

// ======================= x = a + b + c (f32 + bf16 copies) =================
__global__ __launch_bounds__(256) void init_x_kernel(
    const float4* __restrict__ a, const float4* __restrict__ b,
    const float4* __restrict__ c, float4* __restrict__ x,
    unsigned short* __restrict__ xb, long long n4)
{
  long long stride = (long long)gridDim.x * 256;
  for (long long i = (long long)blockIdx.x * 256 + threadIdx.x; i < n4; i += stride) {
    float4 av = a[i], bv = b[i], cv = c[i];
    float4 r;
    r.x = av.x + bv.x + cv.x; r.y = av.y + bv.y + cv.y;
    r.z = av.z + bv.z + cv.z; r.w = av.w + bv.w + cv.w;
    x[i] = r;
    ushort4v o; o.x = f2b(r.x); o.y = f2b(r.y); o.z = f2b(r.z); o.w = f2b(r.w);
    *(ushort4v*)(xb + i * 4) = o;
  }
}

// ============== weight transpose fp32[512][512] -> bf16 WT[c][r] ===========
__global__ __launch_bounds__(256) void transpose_w_kernel(
    const float* __restrict__ W, unsigned short* __restrict__ WT)
{
  __shared__ float t[32][33];
  const float* src = W + (size_t)blockIdx.z * 262144;
  unsigned short* dst = WT + (size_t)blockIdx.z * 262144;
  int bx = blockIdx.x * 32, by = blockIdx.y * 32;
  int tx = threadIdx.x, ty = threadIdx.y;   // block 32x8
  #pragma unroll
  for (int i = 0; i < 32; i += 8)
    t[ty + i][tx] = src[(size_t)(by + ty + i) * 512 + bx + tx];
  __syncthreads();
  #pragma unroll
  for (int i = 0; i < 32; i += 8)
    dst[(size_t)(bx + ty + i) * 512 + by + tx] = f2b(t[tx][ty + i]);
}

// ========================== bf16 GEMM:  C = A @ BT^T + bias ================
// A:[M,512] bf16 row-major (staged to LDS, double-buffered, XOR-swizzled),
// BT:[Ncols,512] bf16 row-major (weights; direct global->VGPR, L2-resident),
// C:[M,Ncols] f32|bf16. 128x128 tile, 4 waves (2x2 of 64x64), K fully
// unrolled (8 steps of BK=64) -> all buffer indices compile-time constant.
__device__ __forceinline__ void stage16(const void* g, void* lds_uniform) {
  __builtin_amdgcn_global_load_lds(
      (const __attribute__((address_space(1))) void*)g,
      (__attribute__((address_space(3))) void*)lds_uniform, 16, 0, 0);
}

template<int OUT_BF16>
__global__ __launch_bounds__(256) void gemm_bt_kernel(
    const unsigned short* __restrict__ A,
    const unsigned short* __restrict__ BT,
    const float* __restrict__ bias,
    void* __restrict__ Cv,
    int M, int Ncols)
{
  constexpr int K = 512;
  // As0 | As1 (16KB each); epilogue buffers overlay the whole 32KB
  __shared__ unsigned short smem[16384];

  // bijective XCD-chunked swizzle (m204): consecutive wgid -> same XCD.
  const int nwg = gridDim.x, orig = blockIdx.x;
  const int xcd = orig & 7, lin = orig >> 3;
  const int q = nwg >> 3, r8 = nwg & 7;
  const int wgid = (xcd < r8 ? xcd * (q + 1) : r8 * (q + 1) + (xcd - r8) * q) + lin;

  const int tiles_n = Ncols >> 7;
  const int tm = wgid / tiles_n;
  const int tn = wgid - tm * tiles_n;
  const int row0 = tm << 7, col0 = tn << 7;
  const int lane = threadIdx.x & 63, wid = threadIdx.x >> 6;
  const int wm = (wid >> 1) << 6, wn = (wid & 1) << 6;

  f32x4 acc[4][4];
  #pragma unroll
  for (int i = 0; i < 4; ++i)
    #pragma unroll
    for (int j = 0; j < 4; ++j) acc[i][j] = (f32x4)0.f;

  // A staging plan: 16 segs of 1KB (16KB tile), 4 issues per wave.
  int srow[4], scsw[4], sseg[4];
  #pragma unroll
  for (int i = 0; i < 4; ++i) {
    int seg = (i << 2) | wid;
    int idx = (seg << 6) | lane;     // row = idx>>3, 16B-chunk = idx&7
    int row = idx >> 3, ch = idx & 7;
    sseg[i] = seg; srow[i] = row; scsw[i] = ch ^ (row & 7);  // pre-swizzled src
  }
  // B fragment base pointers (per ni); frag (ni,kk) at k = kt*64+kk*32+(lane>>4)*8
  const unsigned short* bptr[4];
  #pragma unroll
  for (int ni = 0; ni < 4; ++ni)
    bptr[ni] = BT + (size_t)(col0 + wn + (ni << 4) + (lane & 15)) * K + ((lane >> 4) << 3);

  bf16x8 breg[2][4][2];   // [buf][ni][kk] — static after full unroll

  #define STAGE_A(buf, kb_)                                                     \
    _Pragma("unroll")                                                           \
    for (int i = 0; i < 4; ++i) {                                               \
      int ra = row0 + srow[i]; ra = (ra < M) ? ra : (M - 1);                    \
      stage16(A + (size_t)ra * K + (kb_) + (scsw[i] << 3),                      \
              smem + (buf) * 8192 + (sseg[i] << 9));                            \
    }
  #define LOAD_B(buf, kb_)                                                      \
    _Pragma("unroll")                                                           \
    for (int ni = 0; ni < 4; ++ni) {                                            \
      breg[buf][ni][0] = *(const bf16x8*)(bptr[ni] + (kb_));                    \
      breg[buf][ni][1] = *(const bf16x8*)(bptr[ni] + (kb_) + 32);               \
    }

  STAGE_A(0, 0)
  LOAD_B(0, 0)
  asm volatile("s_waitcnt vmcnt(0)" ::: "memory");
  __syncthreads();

  #pragma unroll
  for (int kt = 0; kt < 8; ++kt) {
    const int cur = kt & 1;
    if (kt < 7) {                       // prefetch next K-step (A->LDS, B->regs)
      STAGE_A(cur ^ 1, (kt + 1) << 6)
      LOAD_B(cur ^ 1, (kt + 1) << 6)
    }
    const unsigned short* As = smem + cur * 8192;
    #pragma unroll
    for (int kk = 0; kk < 2; ++kk) {
      const int kb = (kk << 6) + ((lane >> 4) << 4);   // byte off in 128B row
      bf16x8 af[4];
      #pragma unroll
      for (int mi = 0; mi < 4; ++mi) {
        int r = wm + (mi << 4) + (lane & 15);
        af[mi] = *(const bf16x8*)((const char*)As + (r << 7) + (kb ^ ((r & 7) << 4)));
      }
      #pragma unroll
      for (int mi = 0; mi < 4; ++mi)
        #pragma unroll
        for (int ni = 0; ni < 4; ++ni)
          acc[mi][ni] = __builtin_amdgcn_mfma_f32_16x16x32_bf16(
              breg[cur][ni][kk], af[mi], acc[mi][ni], 0, 0, 0);  // swapped: D[n][m]
    }
    asm volatile("s_waitcnt vmcnt(0)" ::: "memory");
    __syncthreads();
  }
  #undef STAGE_A
  #undef LOAD_B

  const int mrow = lane & 15;            // local row within 16-block
  const int g4 = (lane >> 4) << 2;       // col sub-offset {0,4,8,12}

  if (OUT_BF16) {
    // per-wave XOR-swizzled LDS [64 rows][64 ushorts], then coalesced 16B stores
    unsigned short* ep = smem + wid * 4096;
    #pragma unroll
    for (int ni = 0; ni < 4; ++ni) {
      const float4 bv = *(const float4*)(bias + col0 + wn + (ni << 4) + g4);
      const int c0 = 2 * ni + (g4 >> 3);           // 16B chunk index (0..7)
      #pragma unroll
      for (int mi = 0; mi < 4; ++mi) {
        int row = (mi << 4) + mrow;
        ushort4v p;
        p.x = f2b(acc[mi][ni][0] + bv.x);
        p.y = f2b(acc[mi][ni][1] + bv.y);
        p.z = f2b(acc[mi][ni][2] + bv.z);
        p.w = f2b(acc[mi][ni][3] + bv.w);
        *(ushort4v*)(ep + (row << 6) + ((c0 ^ (row & 7)) << 3) + (g4 & 4)) = p;
      }
    }
    __builtin_amdgcn_s_waitcnt(0);   // own-wave ds_writes visible
    unsigned short* C = (unsigned short*)Cv;
    #pragma unroll
    for (int rr = 0; rr < 8; ++rr) {
      int rloc = (rr << 3) + (lane >> 3);
      int c = lane & 7;
      int rowg = row0 + wm + rloc;
      if (rowg < M) {
        ushort8v val = *(const ushort8v*)(ep + (rloc << 6) + ((c ^ (rloc & 7)) << 3));
        *(ushort8v*)(C + (size_t)rowg * Ncols + col0 + wn + (c << 3)) = val;
      }
    }
  } else {
    // f32: direct float4 stores (4 consecutive cols/lane, 64B sectors filled)
    float* C = (float*)Cv;
    #pragma unroll
    for (int ni = 0; ni < 4; ++ni) {
      const int cb = col0 + wn + (ni << 4) + g4;
      const float4 bv = *(const float4*)(bias + cb);
      #pragma unroll
      for (int mi = 0; mi < 4; ++mi) {
        int rowg = row0 + wm + (mi << 4) + mrow;
        if (rowg < M) {
          float4 v;
          v.x = acc[mi][ni][0] + bv.x;
          v.y = acc[mi][ni][1] + bv.y;
          v.z = acc[mi][ni][2] + bv.z;
          v.w = acc[mi][ni][3] + bv.w;
          *(float4*)(C + (size_t)rowg * Ncols + cb) = v;
        }
      }
    }
  }
}

// ================= per-edge scores: sc[e][h] = q[dst].k[src]/8 ==============
__global__ __launch_bounds__(256) void edge_scores_kernel(
    const unsigned short* __restrict__ qkv, const int* __restrict__ ei,
    int E, float* __restrict__ sc)
{
  int wid = threadIdx.x >> 6, lane = threadIdx.x & 63;
  int e = (blockIdx.x << 2) | wid;
  if (e >= E) return;
  int src = ei[e], dst = ei[E + e];
  ushort8v qv = *(const ushort8v*)(qkv + (size_t)dst * 1536 + (lane << 3));
  ushort8v kv = *(const ushort8v*)(qkv + (size_t)src * 1536 + 512 + (lane << 3));
  float p = 0.f;
  #pragma unroll
  for (int j = 0; j < 8; ++j) p += b2f(qv[j]) * b2f(kv[j]);
  p += __shfl_xor(p, 1);
  p += __shfl_xor(p, 2);
  p += __shfl_xor(p, 4);           // reduce within 8-lane head group
  if (!(lane & 7)) sc[(size_t)e * 8 + (lane >> 3)] = p * 0.125f;
}

// ==================== global softmax over edge axis (per head) ==============
template<int OP>   // 0 = max, 1 = sum
__device__ __forceinline__ void reduce8_block(float (&v)[8], float* red) {
  int lane = threadIdx.x & 63, wid = threadIdx.x >> 6;
  #pragma unroll
  for (int h = 0; h < 8; ++h)
    #pragma unroll
    for (int off = 1; off < 64; off <<= 1) {
      float o = __shfl_xor(v[h], off);
      v[h] = OP ? (v[h] + o) : fmaxf(v[h], o);
    }
  if (lane == 0) {
    #pragma unroll
    for (int h = 0; h < 8; ++h) red[h * 4 + wid] = v[h];
  }
  __syncthreads();
  if (threadIdx.x == 0) {
    #pragma unroll
    for (int h = 0; h < 8; ++h) {
      float r = red[h * 4];
      #pragma unroll
      for (int w = 1; w < 4; ++w)
        r = OP ? (r + red[h * 4 + w]) : fmaxf(r, red[h * 4 + w]);
      v[h] = r;
    }
  }
}

__global__ __launch_bounds__(256) void sm_max_partial_kernel(
    const float* __restrict__ sc, int E, float* __restrict__ part)
{
  __shared__ float red[32];
  float v[8];
  #pragma unroll
  for (int h = 0; h < 8; ++h) v[h] = -1e30f;
  int stride = gridDim.x * 256;
  for (int e = blockIdx.x * 256 + threadIdx.x; e < E; e += stride) {
    #pragma unroll
    for (int h = 0; h < 8; ++h) v[h] = fmaxf(v[h], sc[(size_t)e * 8 + h]);
  }
  reduce8_block<0>(v, red);
  if (threadIdx.x == 0) {
    #pragma unroll
    for (int h = 0; h < 8; ++h) part[blockIdx.x * 8 + h] = v[h];
  }
}

// exp pass with the global-max reduction fused in (reads 256-block partials)
__global__ __launch_bounds__(256) void sm_exp_partial_kernel(
    float* __restrict__ sc, int E, const float* __restrict__ partm,
    float* __restrict__ parts)
{
  __shared__ float red[32];
  __shared__ float gmx[8];
  float v[8];
  #pragma unroll
  for (int h = 0; h < 8; ++h) v[h] = partm[threadIdx.x * 8 + h];
  reduce8_block<0>(v, red);
  if (threadIdx.x == 0) {
    #pragma unroll
    for (int h = 0; h < 8; ++h) gmx[h] = v[h];
  }
  __syncthreads();
  float gm[8];
  #pragma unroll
  for (int h = 0; h < 8; ++h) { gm[h] = gmx[h]; v[h] = 0.f; }
  int stride = gridDim.x * 256;
  for (int e = blockIdx.x * 256 + threadIdx.x; e < E; e += stride) {
    #pragma unroll
    for (int h = 0; h < 8; ++h) {
      float w = __expf(sc[(size_t)e * 8 + h] - gm[h]);
      sc[(size_t)e * 8 + h] = w;           // in-place exp
      v[h] += w;
    }
  }
  reduce8_block<1>(v, red);
  if (threadIdx.x == 0) {
    #pragma unroll
    for (int h = 0; h < 8; ++h) parts[blockIdx.x * 8 + h] = v[h];
  }
}

template<int OP>   // 1: out = 1/sum
__global__ __launch_bounds__(256) void sm_final_kernel(
    const float* __restrict__ part, float* __restrict__ out)
{
  __shared__ float red[32];
  float v[8];
  #pragma unroll
  for (int h = 0; h < 8; ++h) v[h] = part[threadIdx.x * 8 + h];
  reduce8_block<OP>(v, red);
  if (threadIdx.x == 0) {
    #pragma unroll
    for (int h = 0; h < 8; ++h) out[h] = OP ? (1.0f / v[h]) : v[h];
  }
}

// =============================== CSR build ==================================
__global__ __launch_bounds__(256) void hist_kernel(
    const int* __restrict__ ei, int E, int* __restrict__ deg)
{
  int e = blockIdx.x * 256 + threadIdx.x;
  if (e < E) atomicAdd(&deg[ei[E + e]], 1);
}

// 3-kernel scan: per-block scan (shfl), scan of block sums, offset add
__global__ __launch_bounds__(1024) void scan_part_kernel(
    const int* __restrict__ deg, int N, int* __restrict__ rowptr,
    int* __restrict__ bsums)
{
  __shared__ int wsum[16];
  int i = blockIdx.x * 1024 + threadIdx.x;
  int lane = threadIdx.x & 63, wid = threadIdx.x >> 6;
  int sv = (i < N) ? deg[i] : 0;
  #pragma unroll
  for (int off = 1; off < 64; off <<= 1) {
    int t = __shfl_up(sv, off);
    if (lane >= off) sv += t;
  }
  if (lane == 63) wsum[wid] = sv;
  __syncthreads();
  if (threadIdx.x < 16) {
    int ws = wsum[threadIdx.x];
    #pragma unroll
    for (int off = 1; off < 16; off <<= 1) {
      int t = __shfl_up(ws, off);
      if (threadIdx.x >= off) ws += t;
    }
    wsum[threadIdx.x] = ws;
  }
  __syncthreads();
  if (wid > 0) sv += wsum[wid - 1];
  if (i < N) rowptr[i + 1] = sv;
  if (threadIdx.x == 1023) bsums[blockIdx.x] = sv;
}

__global__ __launch_bounds__(64) void scan_bsums_kernel(int* bsums, int nb)
{
  int lane = threadIdx.x;
  int v = (lane < nb) ? bsums[lane] : 0;
  #pragma unroll
  for (int off = 1; off < 64; off <<= 1) {
    int t = __shfl_up(v, off);
    if (lane >= off) v += t;
  }
  int ex = __shfl_up(v, 1);
  if (lane == 0) ex = 0;
  if (lane < nb) bsums[lane] = ex;     // exclusive offsets, in place
}

__global__ __launch_bounds__(1024) void scan_add_kernel(
    int* __restrict__ rowptr, const int* __restrict__ bsums, int N)
{
  int i = blockIdx.x * 1024 + threadIdx.x;
  if (i == 0) rowptr[0] = 0;
  if (i < N && blockIdx.x > 0) rowptr[i + 1] += bsums[blockIdx.x];
}

__global__ __launch_bounds__(256) void scatter_kernel(
    const int* __restrict__ ei, int E, const int* __restrict__ rowptr,
    int* __restrict__ cur, int* __restrict__ eids)
{
  int e = blockIdx.x * 256 + threadIdx.x;
  if (e < E) {
    int dst = ei[E + e];
    int pos = atomicAdd(&cur[dst], 1);
    eids[rowptr[dst] + pos] = e;
  }
}

// ============ aggregate: agg[n] = sum_{e:dst=n} w[e,h] * v[src(e)] ==========
__global__ __launch_bounds__(256) void aggregate_kernel(
    const unsigned short* __restrict__ qkv, const float* __restrict__ wexp,
    const float* __restrict__ ginv, const int* __restrict__ ei,
    const int* __restrict__ rowptr, const int* __restrict__ eids,
    int N, unsigned short* __restrict__ agg)
{
  int wid = threadIdx.x >> 6, lane = threadIdx.x & 63;
  int n = (blockIdx.x << 2) | wid;
  if (n >= N) return;
  int beg = rowptr[n], end = rowptr[n + 1];
  int h = lane >> 3;
  float inv = ginv[h];
  float acc[8] = {0.f,0.f,0.f,0.f,0.f,0.f,0.f,0.f};
  int i = beg;
  for (; i + 2 <= end; i += 2) {       // 2-edge ILP
    int e0 = eids[i], e1 = eids[i + 1];
    int s0 = ei[e0], s1 = ei[e1];
    float w0 = wexp[(size_t)e0 * 8 + h] * inv;
    float w1 = wexp[(size_t)e1 * 8 + h] * inv;
    ushort8v v0 = *(const ushort8v*)(qkv + (size_t)s0 * 1536 + 1024 + (lane << 3));
    ushort8v v1 = *(const ushort8v*)(qkv + (size_t)s1 * 1536 + 1024 + (lane << 3));
    #pragma unroll
    for (int j = 0; j < 8; ++j) acc[j] += w0 * b2f(v0[j]) + w1 * b2f(v1[j]);
  }
  if (i < end) {
    int e0 = eids[i];
    int s0 = ei[e0];
    float w0 = wexp[(size_t)e0 * 8 + h] * inv;
    ushort8v v0 = *(const ushort8v*)(qkv + (size_t)s0 * 1536 + 1024 + (lane << 3));
    #pragma unroll
    for (int j = 0; j < 8; ++j) acc[j] += w0 * b2f(v0[j]);
  }
  ushort8v o;
  #pragma unroll
  for (int j = 0; j < 8; ++j) o[j] = f2b(acc[j]);
  *(ushort8v*)(agg + (size_t)n * 512 + (lane << 3)) = o;
}

// ====================== LN(proj + resid)*g + bt  (wave/row) =================
__global__ __launch_bounds__(256) void ln_kernel(
    const unsigned short* __restrict__ proj, const float* __restrict__ g,
    const float* __restrict__ bt, float* __restrict__ x,
    unsigned short* __restrict__ xb, int N)
{
  int wid = threadIdx.x >> 6, lane = threadIdx.x & 63;
  int n = (blockIdx.x << 2) | wid;
  if (n >= N) return;
  size_t base = (size_t)n * 512 + (lane << 3);
  ushort8v pv = *(const ushort8v*)(proj + base);
  const float4* xp = (const float4*)(x + base);
  float4 x0 = xp[0], x1 = xp[1];
  float y[8] = {b2f(pv[0]) + x0.x, b2f(pv[1]) + x0.y, b2f(pv[2]) + x0.z,
                b2f(pv[3]) + x0.w, b2f(pv[4]) + x1.x, b2f(pv[5]) + x1.y,
                b2f(pv[6]) + x1.z, b2f(pv[7]) + x1.w};
  float s = 0.f;
  #pragma unroll
  for (int j = 0; j < 8; ++j) s += y[j];
  #pragma unroll
  for (int off = 1; off < 64; off <<= 1) s += __shfl_xor(s, off);
  float mean = s * (1.f / 512.f);
  float vs = 0.f;
  #pragma unroll
  for (int j = 0; j < 8; ++j) { float d = y[j] - mean; vs += d * d; }
  #pragma unroll
  for (int off = 1; off < 64; off <<= 1) vs += __shfl_xor(vs, off);
  float rstd = rsqrtf(vs * (1.f / 512.f) + 1e-5f);
  int gi = lane << 3;
  float o[8];
  #pragma unroll
  for (int j = 0; j < 8; ++j) o[j] = (y[j] - mean) * rstd * g[gi + j] + bt[gi + j];
  float4 r0 = {o[0], o[1], o[2], o[3]}, r1 = {o[4], o[5], o[6], o[7]};
  *(float4*)(x + base) = r0;
  *(float4*)(x + base + 4) = r1;
  ushort8v ob;
  #pragma unroll
  for (int j = 0; j < 8; ++j) ob[j] = f2b(o[j]);
  *(ushort8v*)(xb + base) = ob;
}

// ================================ driver ====================================
extern "C" void kernel_launch(void* const* d_in, const int* in_sizes, int n_in,
                              void* d_out, int out_size, void* d_ws, size_t ws_size,
                              hipStream_t stream)
{
  (void)n_in; (void)out_size;
  const float* feat[3] = {(const float*)d_in[0], (const float*)d_in[1], (const float*)d_in[2]};
  const float* emb[3]  = {(const float*)d_in[3], (const float*)d_in[4], (const float*)d_in[5]};
  const float* pos[3]  = {(const float*)d_in[6], (const float*)d_in[7], (const float*)d_in[8]};
  const float* W[3]  = {(const float*)d_in[9],  (const float*)d_in[13], (const float*)d_in[17]};
  const float* Bb[3] = {(const float*)d_in[10], (const float*)d_in[14], (const float*)d_in[18]};
  const float* G[3]  = {(const float*)d_in[11], (const float*)d_in[15], (const float*)d_in[19]};
  const float* Bt[3] = {(const float*)d_in[12], (const float*)d_in[16], (const float*)d_in[20]};
  const float* headW = (const float*)d_in[21];
  const float* headB = (const float*)d_in[22];
  const int* ei[3] = {(const int*)d_in[23], (const int*)d_in[24], (const int*)d_in[25]};

  int Ns[3], Es[3];
  for (int s = 0; s < 3; ++s) { Ns[s] = in_sizes[s] / 512; Es[s] = in_sizes[23 + s] / 2; }
  int NMAX = Ns[0], EMAX = Es[0];
  for (int s = 1; s < 3; ++s) { if (Ns[s] > NMAX) NMAX = Ns[s]; if (Es[s] > EMAX) EMAX = Es[s]; }

  char* base = (char*)d_ws;
  size_t off = 0;
  auto carve = [&](size_t bytes) -> char* {
    char* r = base + off;
    off += (bytes + 255) & ~(size_t)255;
    return r;
  };
  unsigned short* WT  = (unsigned short*)carve((size_t)27 * 262144 * 2);
  float*          X   = (float*)carve((size_t)NMAX * 512 * 4);
  unsigned short* XB  = (unsigned short*)carve((size_t)NMAX * 512 * 2);
  unsigned short* QKV = (unsigned short*)carve((size_t)NMAX * 1536 * 2);
  float*          SC  = (float*)carve((size_t)EMAX * 8 * 4);
  unsigned short* AGG = (unsigned short*)carve((size_t)NMAX * 512 * 2);
  int*   ROWPTR = (int*)carve((size_t)(NMAX + 1) * 4);
  int*   DEG    = (int*)carve((size_t)NMAX * 4);
  int*   EIDS   = (int*)carve((size_t)EMAX * 4);
  int*   BSUMS  = (int*)carve(64 * 4);
  float* PARTM  = (float*)carve(256 * 8 * 4);
  float* PARTS  = (float*)carve(256 * 8 * 4);
  float* GINV   = (float*)carve(256);
  unsigned short* PROJ = QKV;    // alias: q/k/v slots dead once aggregate done
  if (off > ws_size) return;     // insufficient workspace: fail loudly

  // weights -> bf16 transposed [col][row] ("BT" layout for the GEMM)
  transpose_w_kernel<<<dim3(16,16,8), dim3(32,8), 0, stream>>>(W[0], WT);
  transpose_w_kernel<<<dim3(16,16,8), dim3(32,8), 0, stream>>>(W[1], WT + (size_t)8 * 262144);
  transpose_w_kernel<<<dim3(16,16,8), dim3(32,8), 0, stream>>>(W[2], WT + (size_t)16 * 262144);
  transpose_w_kernel<<<dim3(16,16,3), dim3(32,8), 0, stream>>>(headW, WT + (size_t)24 * 262144);

  size_t out_off = 0;
  for (int s = 0; s < 3; ++s) {
    const int N = Ns[s], E = Es[s];
    const int mt = (N + 127) >> 7;
    const int nb = (N + 1023) / 1024;

    init_x_kernel<<<2048, 256, 0, stream>>>(
        (const float4*)feat[s], (const float4*)emb[s], (const float4*)pos[s],
        (float4*)X, XB, (long long)N * 128);

    // CSR by dst (edge index is constant per stream; built once, used 2x)
    hipMemsetAsync(DEG, 0, (size_t)N * 4, stream);
    hist_kernel<<<(E + 255) / 256, 256, 0, stream>>>(ei[s], E, DEG);
    scan_part_kernel<<<nb, 1024, 0, stream>>>(DEG, N, ROWPTR, BSUMS);
    scan_bsums_kernel<<<1, 64, 0, stream>>>(BSUMS, nb);
    scan_add_kernel<<<nb, 1024, 0, stream>>>(ROWPTR, BSUMS, N);
    hipMemsetAsync(DEG, 0, (size_t)N * 4, stream);
    scatter_kernel<<<(E + 255) / 256, 256, 0, stream>>>(ei[s], E, ROWPTR, DEG, EIDS);

    for (int l = 0; l < 2; ++l) {
      const unsigned short* Wqkv = WT + (size_t)(s * 8 + l * 4) * 262144;
      const unsigned short* Wo   = WT + (size_t)(s * 8 + l * 4 + 3) * 262144;
      const float* bqkv = Bb[s] + (size_t)l * 4 * 512;       // q,k,v biases contiguous
      const float* bo   = Bb[s] + (size_t)(l * 4 + 3) * 512;

      gemm_bt_kernel<1><<<dim3(mt * 12), 256, 0, stream>>>(XB, Wqkv, bqkv, QKV, N, 1536);
      edge_scores_kernel<<<(E + 3) / 4, 256, 0, stream>>>(QKV, ei[s], E, SC);
      sm_max_partial_kernel<<<256, 256, 0, stream>>>(SC, E, PARTM);
      sm_exp_partial_kernel<<<256, 256, 0, stream>>>(SC, E, PARTM, PARTS);
      sm_final_kernel<1><<<1, 256, 0, stream>>>(PARTS, GINV);
      aggregate_kernel<<<(N + 3) / 4, 256, 0, stream>>>(QKV, SC, GINV, ei[s], ROWPTR, EIDS, N, AGG);
      gemm_bt_kernel<1><<<dim3(mt * 4), 256, 0, stream>>>(AGG, Wo, bo, PROJ, N, 512);
      ln_kernel<<<(N + 3) / 4, 256, 0, stream>>>(PROJ, G[s] + (size_t)l * 512,
                                                 Bt[s] + (size_t)l * 512, X, XB, N);
    }

    gemm_bt_kernel<0><<<dim3(mt * 4), 256, 0, stream>>>(
        XB, WT + (size_t)(24 + s) * 262144, headB + (size_t)s * 512,
        (float*)d_out + out_off, N, 512);
    out_off += (size_t)N * 512;
  }
}

// Round 6
// 1612.371 us; speedup vs baseline: 1.2107x; 1.2107x over previous
//
#include <hip/hip_runtime.h>

// ---------------------------------------------------------------------------
// SimplicialAttentionTransformer: 3 streams x (embed-add, 2x[QKV gemm,
// CSR-ordered edge scores, GLOBAL softmax over edges, CSR segment-sum,
// proj gemm, LN], head gemm). bf16 MFMA GEMM: A+B staged to LDS via
// global_load_lds (single 32KB buffer, BK=64), swapped-operand MFMA so each
// lane owns 4 consecutive output columns -> direct 8B stores (no LDS epilogue).
// ---------------------------------------------------------------------------

typedef __attribute__((ext_vector_type(8))) __bf16 bf16x8;
typedef __attribute__((ext_vector_type(4))) float f32x4;
typedef __attribute__((ext_vector_type(8))) unsigned short ushort8v;
typedef __attribute__((ext_vector_type(4))) unsigned short ushort4v;

__device__ __forceinline__ float b2f(unsigned short u) {
  union { unsigned u; float f; } x; x.u = (unsigned)u << 16; return x.f;
}
__device__ __forceinline__ unsigned short f2b(float f) {
  union { float f; unsigned u; } x; x.f = f;
  unsigned r = x.u + 0x7fffu + ((x.u >> 16) & 1u);   // RNE
  return (unsigned short)(r >> 16);
}

// ======================= x = a + b + c (f32 + bf16 copies) =================
__global__ __launch_bounds__(256) void init_x_kernel(
    const float4* __restrict__ a, const float4* __restrict__ b,
    const float4* __restrict__ c, float4* __restrict__ x,
    unsigned short* __restrict__ xb, long long n4)
{
  long long stride = (long long)gridDim.x * 256;
  for (long long i = (long long)blockIdx.x * 256 + threadIdx.x; i < n4; i += stride) {
    float4 av = a[i], bv = b[i], cv = c[i];
    float4 r;
    r.x = av.x + bv.x + cv.x; r.y = av.y + bv.y + cv.y;
    r.z = av.z + bv.z + cv.z; r.w = av.w + bv.w + cv.w;
    x[i] = r;
    ushort4v o; o.x = f2b(r.x); o.y = f2b(r.y); o.z = f2b(r.z); o.w = f2b(r.w);
    *(ushort4v*)(xb + i * 4) = o;
  }
}

// ============== weight transpose fp32[512][512] -> bf16 WT[c][r] ===========
__global__ __launch_bounds__(256) void transpose_w_kernel(
    const float* __restrict__ W, unsigned short* __restrict__ WT)
{
  __shared__ float t[32][33];
  const float* src = W + (size_t)blockIdx.z * 262144;
  unsigned short* dst = WT + (size_t)blockIdx.z * 262144;
  int bx = blockIdx.x * 32, by = blockIdx.y * 32;
  int tx = threadIdx.x, ty = threadIdx.y;   // block 32x8
  #pragma unroll
  for (int i = 0; i < 32; i += 8)
    t[ty + i][tx] = src[(size_t)(by + ty + i) * 512 + bx + tx];
  __syncthreads();
  #pragma unroll
  for (int i = 0; i < 32; i += 8)
    dst[(size_t)(bx + ty + i) * 512 + by + tx] = f2b(t[tx][ty + i]);
}

// ========================== bf16 GEMM:  C = A @ BT^T + bias ================
// A:[M,512] bf16 row-major, BT:[Ncols,512] bf16 row-major, C:[M,Ncols]
// f32|bf16. 128x128 tile, BK=64, 4 waves (2x2 of 64x64). Both operands
// staged via global_load_lds with XOR-swizzled global source (linear LDS
// dest) + swizzled ds_read_b128. Swapped-operand MFMA: lane holds
// (rows = mi*16 + lane&15, cols = ni*16 + (lane>>4)*4 + reg).
__device__ __forceinline__ void stage16(const void* g, void* lds_uniform) {
  __builtin_amdgcn_global_load_lds(
      (const __attribute__((address_space(1))) void*)g,
      (__attribute__((address_space(3))) void*)lds_uniform, 16, 0, 0);
}

template<int OUT_BF16>
__global__ __launch_bounds__(256) void gemm_bt_kernel(
    const unsigned short* __restrict__ A,
    const unsigned short* __restrict__ BT,
    const float* __restrict__ bias,
    void* __restrict__ Cv,
    int M, int Ncols)
{
  constexpr int K = 512;
  __shared__ unsigned short As[8192];   // 128 rows x 64 bf16 (128B rows)
  __shared__ unsigned short Bs[8192];

  // bijective XCD-chunked swizzle (m204): consecutive wgid -> same XCD,
  // consecutive wgid share tm (same A panel) -> per-XCD L2 reuse.
  const int nwg = gridDim.x, orig = blockIdx.x;
  const int xcd = orig & 7, lin = orig >> 3;
  const int q = nwg >> 3, r8 = nwg & 7;
  const int wgid = (xcd < r8 ? xcd * (q + 1) : r8 * (q + 1) + (xcd - r8) * q) + lin;

  const int tiles_n = Ncols >> 7;
  const int tm = wgid / tiles_n;
  const int tn = wgid - tm * tiles_n;
  const int row0 = tm << 7, col0 = tn << 7;
  const int lane = threadIdx.x & 63, wid = threadIdx.x >> 6;
  const int wm = (wid >> 1) << 6, wn = (wid & 1) << 6;

  f32x4 acc[4][4];
  #pragma unroll
  for (int i = 0; i < 4; ++i)
    #pragma unroll
    for (int j = 0; j < 4; ++j) acc[i][j] = (f32x4)0.f;

  // staging plan: 16 segs of 1KB per operand, 4 wave-issues each.
  int srow[4], scsw[4], sseg[4];
  #pragma unroll
  for (int i = 0; i < 4; ++i) {
    int seg = (i << 2) | wid;
    int idx = (seg << 6) | lane;     // row = idx>>3, 16B-chunk = idx&7
    int row = idx >> 3, ch = idx & 7;
    sseg[i] = seg; srow[i] = row; scsw[i] = ch ^ (row & 7);  // pre-swizzled src
  }

  #pragma unroll
  for (int kt = 0; kt < 8; ++kt) {
    const int kbase = kt << 6;
    #pragma unroll
    for (int i = 0; i < 4; ++i) {
      int ra = row0 + srow[i]; ra = (ra < M) ? ra : (M - 1);
      stage16(A + (size_t)ra * K + kbase + (scsw[i] << 3), As + (sseg[i] << 9));
      int rb = col0 + srow[i];
      stage16(BT + (size_t)rb * K + kbase + (scsw[i] << 3), Bs + (sseg[i] << 9));
    }
    asm volatile("s_waitcnt vmcnt(0)" ::: "memory");
    __syncthreads();

    #pragma unroll
    for (int kk = 0; kk < 2; ++kk) {
      const int kb = (kk << 6) + ((lane >> 4) << 4);   // byte off in 128B row
      bf16x8 af[4], bfr[4];
      #pragma unroll
      for (int mi = 0; mi < 4; ++mi) {
        int r = wm + (mi << 4) + (lane & 15);
        af[mi] = *(const bf16x8*)((const char*)As + (r << 7) + (kb ^ ((r & 7) << 4)));
      }
      #pragma unroll
      for (int ni = 0; ni < 4; ++ni) {
        int r = wn + (ni << 4) + (lane & 15);
        bfr[ni] = *(const bf16x8*)((const char*)Bs + (r << 7) + (kb ^ ((r & 7) << 4)));
      }
      #pragma unroll
      for (int mi = 0; mi < 4; ++mi)
        #pragma unroll
        for (int ni = 0; ni < 4; ++ni)
          acc[mi][ni] = __builtin_amdgcn_mfma_f32_16x16x32_bf16(
              bfr[ni], af[mi], acc[mi][ni], 0, 0, 0);  // swapped: D[n][m]
    }
    __syncthreads();
  }

  const int mrow = lane & 15;            // local row within 16-block
  const int g4 = (lane >> 4) << 2;       // col sub-offset {0,4,8,12}

  if (OUT_BF16) {
    // direct 8B stores: 4 consecutive bf16 cols per lane; adjacent lane
    // groups + ni stores merge to full sectors in L2.
    unsigned short* C = (unsigned short*)Cv;
    #pragma unroll
    for (int ni = 0; ni < 4; ++ni) {
      const int cb = col0 + wn + (ni << 4) + g4;
      const float4 bv = *(const float4*)(bias + cb);
      #pragma unroll
      for (int mi = 0; mi < 4; ++mi) {
        int rowg = row0 + wm + (mi << 4) + mrow;
        if (rowg < M) {
          ushort4v p;
          p.x = f2b(acc[mi][ni][0] + bv.x);
          p.y = f2b(acc[mi][ni][1] + bv.y);
          p.z = f2b(acc[mi][ni][2] + bv.z);
          p.w = f2b(acc[mi][ni][3] + bv.w);
          *(ushort4v*)(C + (size_t)rowg * Ncols + cb) = p;
        }
      }
    }
  } else {
    // f32: direct float4 stores (4 consecutive cols/lane)
    float* C = (float*)Cv;
    #pragma unroll
    for (int ni = 0; ni < 4; ++ni) {
      const int cb = col0 + wn + (ni << 4) + g4;
      const float4 bv = *(const float4*)(bias + cb);
      #pragma unroll
      for (int mi = 0; mi < 4; ++mi) {
        int rowg = row0 + wm + (mi << 4) + mrow;
        if (rowg < M) {
          float4 v;
          v.x = acc[mi][ni][0] + bv.x;
          v.y = acc[mi][ni][1] + bv.y;
          v.z = acc[mi][ni][2] + bv.z;
          v.w = acc[mi][ni][3] + bv.w;
          *(float4*)(C + (size_t)rowg * Ncols + cb) = v;
        }
      }
    }
  }
}

// ====== CSR-ordered edge scores: sc[i][h] = q[n] . k[src(i)] / 8 ===========
// One wave per dst node n: q[n] loaded once to regs, k gathered per in-edge.
// sc stored at CSR position i (softmax is global over edges -> order-free).
__global__ __launch_bounds__(256) void csr_scores_kernel(
    const unsigned short* __restrict__ qkv, const int* __restrict__ srcs,
    const int* __restrict__ rowptr, int N, float* __restrict__ sc)
{
  int wid = threadIdx.x >> 6, lane = threadIdx.x & 63;
  int n = (blockIdx.x << 2) | wid;
  if (n >= N) return;
  int beg = rowptr[n], end = rowptr[n + 1];
  if (beg == end) return;
  ushort8v qv = *(const ushort8v*)(qkv + (size_t)n * 1536 + (lane << 3));
  float qf[8];
  #pragma unroll
  for (int j = 0; j < 8; ++j) qf[j] = b2f(qv[j]);
  int i = beg;
  for (; i + 2 <= end; i += 2) {       // 2-edge ILP
    int s0 = srcs[i], s1 = srcs[i + 1];
    ushort8v k0 = *(const ushort8v*)(qkv + (size_t)s0 * 1536 + 512 + (lane << 3));
    ushort8v k1 = *(const ushort8v*)(qkv + (size_t)s1 * 1536 + 512 + (lane << 3));
    float p0 = 0.f, p1 = 0.f;
    #pragma unroll
    for (int j = 0; j < 8; ++j) { p0 += qf[j] * b2f(k0[j]); p1 += qf[j] * b2f(k1[j]); }
    p0 += __shfl_xor(p0, 1); p1 += __shfl_xor(p1, 1);
    p0 += __shfl_xor(p0, 2); p1 += __shfl_xor(p1, 2);
    p0 += __shfl_xor(p0, 4); p1 += __shfl_xor(p1, 4);
    if (!(lane & 7)) {
      sc[(size_t)i * 8 + (lane >> 3)] = p0 * 0.125f;
      sc[(size_t)(i + 1) * 8 + (lane >> 3)] = p1 * 0.125f;
    }
  }
  if (i < end) {
    int s0 = srcs[i];
    ushort8v k0 = *(const ushort8v*)(qkv + (size_t)s0 * 1536 + 512 + (lane << 3));
    float p0 = 0.f;
    #pragma unroll
    for (int j = 0; j < 8; ++j) p0 += qf[j] * b2f(k0[j]);
    p0 += __shfl_xor(p0, 1);
    p0 += __shfl_xor(p0, 2);
    p0 += __shfl_xor(p0, 4);
    if (!(lane & 7)) sc[(size_t)i * 8 + (lane >> 3)] = p0 * 0.125f;
  }
}

// ==================== global softmax over edge axis (per head) ==============
template<int OP>   // 0 = max, 1 = sum
__device__ __forceinline__ void reduce8_block(float (&v)[8], float* red) {
  int lane = threadIdx.x & 63, wid = threadIdx.x >> 6;
  #pragma unroll
  for (int h = 0; h < 8; ++h)
    #pragma unroll
    for (int off = 1; off < 64; off <<= 1) {
      float o = __shfl_xor(v[h], off);
      v[h] = OP ? (v[h] + o) : fmaxf(v[h], o);
    }
  if (lane == 0) {
    #pragma unroll
    for (int h = 0; h < 8; ++h) red[h * 4 + wid] = v[h];
  }
  __syncthreads();
  if (threadIdx.x == 0) {
    #pragma unroll
    for (int h = 0; h < 8; ++h) {
      float r = red[h * 4];
      #pragma unroll
      for (int w = 1; w < 4; ++w)
        r = OP ? (r + red[h * 4 + w]) : fmaxf(r, red[h * 4 + w]);
      v[h] = r;
    }
  }
}

__global__ __launch_bounds__(256) void sm_max_partial_kernel(
    const float* __restrict__ sc, int E, float* __restrict__ part)
{
  __shared__ float red[32];
  float v[8];
  #pragma unroll
  for (int h = 0; h < 8; ++h) v[h] = -1e30f;
  int stride = gridDim.x * 256;
  for (int e = blockIdx.x * 256 + threadIdx.x; e < E; e += stride) {
    #pragma unroll
    for (int h = 0; h < 8; ++h) v[h] = fmaxf(v[h], sc[(size_t)e * 8 + h]);
  }
  reduce8_block<0>(v, red);
  if (threadIdx.x == 0) {
    #pragma unroll
    for (int h = 0; h < 8; ++h) part[blockIdx.x * 8 + h] = v[h];
  }
}

// exp pass with the global-max reduction fused in (reads 256-block partials)
__global__ __launch_bounds__(256) void sm_exp_partial_kernel(
    float* __restrict__ sc, int E, const float* __restrict__ partm,
    float* __restrict__ parts)
{
  __shared__ float red[32];
  __shared__ float gmx[8];
  float v[8];
  #pragma unroll
  for (int h = 0; h < 8; ++h) v[h] = partm[threadIdx.x * 8 + h];
  reduce8_block<0>(v, red);
  if (threadIdx.x == 0) {
    #pragma unroll
    for (int h = 0; h < 8; ++h) gmx[h] = v[h];
  }
  __syncthreads();
  float gm[8];
  #pragma unroll
  for (int h = 0; h < 8; ++h) { gm[h] = gmx[h]; v[h] = 0.f; }
  int stride = gridDim.x * 256;
  for (int e = blockIdx.x * 256 + threadIdx.x; e < E; e += stride) {
    #pragma unroll
    for (int h = 0; h < 8; ++h) {
      float w = __expf(sc[(size_t)e * 8 + h] - gm[h]);
      sc[(size_t)e * 8 + h] = w;           // in-place exp
      v[h] += w;
    }
  }
  reduce8_block<1>(v, red);
  if (threadIdx.x == 0) {
    #pragma unroll
    for (int h = 0; h < 8; ++h) parts[blockIdx.x * 8 + h] = v[h];
  }
}

template<int OP>   // 1: out = 1/sum
__global__ __launch_bounds__(256) void sm_final_kernel(
    const float* __restrict__ part, float* __restrict__ out)
{
  __shared__ float red[32];
  float v[8];
  #pragma unroll
  for (int h = 0; h < 8; ++h) v[h] = part[threadIdx.x * 8 + h];
  reduce8_block<OP>(v, red);
  if (threadIdx.x == 0) {
    #pragma unroll
    for (int h = 0; h < 8; ++h) out[h] = OP ? (1.0f / v[h]) : v[h];
  }
}

// =============================== CSR build ==================================
__global__ __launch_bounds__(256) void hist_kernel(
    const int* __restrict__ ei, int E, int* __restrict__ deg)
{
  int e = blockIdx.x * 256 + threadIdx.x;
  if (e < E) atomicAdd(&deg[ei[E + e]], 1);
}

// 3-kernel scan: per-block scan (shfl), scan of block sums, offset add
__global__ __launch_bounds__(1024) void scan_part_kernel(
    const int* __restrict__ deg, int N, int* __restrict__ rowptr,
    int* __restrict__ bsums)
{
  __shared__ int wsum[16];
  int i = blockIdx.x * 1024 + threadIdx.x;
  int lane = threadIdx.x & 63, wid = threadIdx.x >> 6;
  int sv = (i < N) ? deg[i] : 0;
  #pragma unroll
  for (int off = 1; off < 64; off <<= 1) {
    int t = __shfl_up(sv, off);
    if (lane >= off) sv += t;
  }
  if (lane == 63) wsum[wid] = sv;
  __syncthreads();
  if (threadIdx.x < 16) {
    int ws = wsum[threadIdx.x];
    #pragma unroll
    for (int off = 1; off < 16; off <<= 1) {
      int t = __shfl_up(ws, off);
      if (threadIdx.x >= off) ws += t;
    }
    wsum[threadIdx.x] = ws;
  }
  __syncthreads();
  if (wid > 0) sv += wsum[wid - 1];
  if (i < N) rowptr[i + 1] = sv;
  if (threadIdx.x == 1023) bsums[blockIdx.x] = sv;
}

__global__ __launch_bounds__(64) void scan_bsums_kernel(int* bsums, int nb)
{
  int lane = threadIdx.x;
  int v = (lane < nb) ? bsums[lane] : 0;
  #pragma unroll
  for (int off = 1; off < 64; off <<= 1) {
    int t = __shfl_up(v, off);
    if (lane >= off) v += t;
  }
  int ex = __shfl_up(v, 1);
  if (lane == 0) ex = 0;
  if (lane < nb) bsums[lane] = ex;     // exclusive offsets, in place
}

__global__ __launch_bounds__(1024) void scan_add_kernel(
    int* __restrict__ rowptr, const int* __restrict__ bsums, int N)
{
  int i = blockIdx.x * 1024 + threadIdx.x;
  if (i == 0) rowptr[0] = 0;
  if (i < N && blockIdx.x > 0) rowptr[i + 1] += bsums[blockIdx.x];
}

// scatter: store SOURCE id directly at CSR slot (scores/aggregate need only src)
__global__ __launch_bounds__(256) void scatter_kernel(
    const int* __restrict__ ei, int E, const int* __restrict__ rowptr,
    int* __restrict__ cur, int* __restrict__ srcs)
{
  int e = blockIdx.x * 256 + threadIdx.x;
  if (e < E) {
    int dst = ei[E + e];
    int pos = atomicAdd(&cur[dst], 1);
    srcs[rowptr[dst] + pos] = ei[e];
  }
}

// ====== aggregate: agg[n] = sum_{i in CSR(n)} w[i,h] * v[srcs[i]] ==========
__global__ __launch_bounds__(256) void aggregate_kernel(
    const unsigned short* __restrict__ qkv, const float* __restrict__ wexp,
    const float* __restrict__ ginv, const int* __restrict__ srcs,
    const int* __restrict__ rowptr, int N, unsigned short* __restrict__ agg)
{
  int wid = threadIdx.x >> 6, lane = threadIdx.x & 63;
  int n = (blockIdx.x << 2) | wid;
  if (n >= N) return;
  int beg = rowptr[n], end = rowptr[n + 1];
  int h = lane >> 3;
  float inv = ginv[h];
  float acc[8] = {0.f,0.f,0.f,0.f,0.f,0.f,0.f,0.f};
  int i = beg;
  for (; i + 2 <= end; i += 2) {       // 2-edge ILP
    int s0 = srcs[i], s1 = srcs[i + 1];
    float w0 = wexp[(size_t)i * 8 + h] * inv;
    float w1 = wexp[(size_t)(i + 1) * 8 + h] * inv;
    ushort8v v0 = *(const ushort8v*)(qkv + (size_t)s0 * 1536 + 1024 + (lane << 3));
    ushort8v v1 = *(const ushort8v*)(qkv + (size_t)s1 * 1536 + 1024 + (lane << 3));
    #pragma unroll
    for (int j = 0; j < 8; ++j) acc[j] += w0 * b2f(v0[j]) + w1 * b2f(v1[j]);
  }
  if (i < end) {
    int s0 = srcs[i];
    float w0 = wexp[(size_t)i * 8 + h] * inv;
    ushort8v v0 = *(const ushort8v*)(qkv + (size_t)s0 * 1536 + 1024 + (lane << 3));
    #pragma unroll
    for (int j = 0; j < 8; ++j) acc[j] += w0 * b2f(v0[j]);
  }
  ushort8v o;
  #pragma unroll
  for (int j = 0; j < 8; ++j) o[j] = f2b(acc[j]);
  *(ushort8v*)(agg + (size_t)n * 512 + (lane << 3)) = o;
}

// ====================== LN(proj + resid)*g + bt  (wave/row) =================
__global__ __launch_bounds__(256) void ln_kernel(
    const unsigned short* __restrict__ proj, const float* __restrict__ g,
    const float* __restrict__ bt, float* __restrict__ x,
    unsigned short* __restrict__ xb, int N)
{
  int wid = threadIdx.x >> 6, lane = threadIdx.x & 63;
  int n = (blockIdx.x << 2) | wid;
  if (n >= N) return;
  size_t base = (size_t)n * 512 + (lane << 3);
  ushort8v pv = *(const ushort8v*)(proj + base);
  const float4* xp = (const float4*)(x + base);
  float4 x0 = xp[0], x1 = xp[1];
  float y[8] = {b2f(pv[0]) + x0.x, b2f(pv[1]) + x0.y, b2f(pv[2]) + x0.z,
                b2f(pv[3]) + x0.w, b2f(pv[4]) + x1.x, b2f(pv[5]) + x1.y,
                b2f(pv[6]) + x1.z, b2f(pv[7]) + x1.w};
  float s = 0.f;
  #pragma unroll
  for (int j = 0; j < 8; ++j) s += y[j];
  #pragma unroll
  for (int off = 1; off < 64; off <<= 1) s += __shfl_xor(s, off);
  float mean = s * (1.f / 512.f);
  float vs = 0.f;
  #pragma unroll
  for (int j = 0; j < 8; ++j) { float d = y[j] - mean; vs += d * d; }
  #pragma unroll
  for (int off = 1; off < 64; off <<= 1) vs += __shfl_xor(vs, off);
  float rstd = rsqrtf(vs * (1.f / 512.f) + 1e-5f);
  int gi = lane << 3;
  float o[8];
  #pragma unroll
  for (int j = 0; j < 8; ++j) o[j] = (y[j] - mean) * rstd * g[gi + j] + bt[gi + j];
  float4 r0 = {o[0], o[1], o[2], o[3]}, r1 = {o[4], o[5], o[6], o[7]};
  *(float4*)(x + base) = r0;
  *(float4*)(x + base + 4) = r1;
  ushort8v ob;
  #pragma unroll
  for (int j = 0; j < 8; ++j) ob[j] = f2b(o[j]);
  *(ushort8v*)(xb + base) = ob;
}

// ================================ driver ====================================
extern "C" void kernel_launch(void* const* d_in, const int* in_sizes, int n_in,
                              void* d_out, int out_size, void* d_ws, size_t ws_size,
                              hipStream_t stream)
{
  (void)n_in; (void)out_size;
  const float* feat[3] = {(const float*)d_in[0], (const float*)d_in[1], (const float*)d_in[2]};
  const float* emb[3]  = {(const float*)d_in[3], (const float*)d_in[4], (const float*)d_in[5]};
  const float* pos[3]  = {(const float*)d_in[6], (const float*)d_in[7], (const float*)d_in[8]};
  const float* W[3]  = {(const float*)d_in[9],  (const float*)d_in[13], (const float*)d_in[17]};
  const float* Bb[3] = {(const float*)d_in[10], (const float*)d_in[14], (const float*)d_in[18]};
  const float* G[3]  = {(const float*)d_in[11], (const float*)d_in[15], (const float*)d_in[19]};
  const float* Bt[3] = {(const float*)d_in[12], (const float*)d_in[16], (const float*)d_in[20]};
  const float* headW = (const float*)d_in[21];
  const float* headB = (const float*)d_in[22];
  const int* ei[3] = {(const int*)d_in[23], (const int*)d_in[24], (const int*)d_in[25]};

  int Ns[3], Es[3];
  for (int s = 0; s < 3; ++s) { Ns[s] = in_sizes[s] / 512; Es[s] = in_sizes[23 + s] / 2; }
  int NMAX = Ns[0], EMAX = Es[0];
  for (int s = 1; s < 3; ++s) { if (Ns[s] > NMAX) NMAX = Ns[s]; if (Es[s] > EMAX) EMAX = Es[s]; }

  char* base = (char*)d_ws;
  size_t off = 0;
  auto carve = [&](size_t bytes) -> char* {
    char* r = base + off;
    off += (bytes + 255) & ~(size_t)255;
    return r;
  };
  unsigned short* WT  = (unsigned short*)carve((size_t)27 * 262144 * 2);
  float*          X   = (float*)carve((size_t)NMAX * 512 * 4);
  unsigned short* XB  = (unsigned short*)carve((size_t)NMAX * 512 * 2);
  unsigned short* QKV = (unsigned short*)carve((size_t)NMAX * 1536 * 2);
  float*          SC  = (float*)carve((size_t)EMAX * 8 * 4);
  unsigned short* AGG = (unsigned short*)carve((size_t)NMAX * 512 * 2);
  int*   ROWPTR = (int*)carve((size_t)(NMAX + 1) * 4);
  int*   DEG    = (int*)carve((size_t)NMAX * 4);
  int*   SRCS   = (int*)carve((size_t)EMAX * 4);
  int*   BSUMS  = (int*)carve(64 * 4);
  float* PARTM  = (float*)carve(256 * 8 * 4);
  float* PARTS  = (float*)carve(256 * 8 * 4);
  float* GINV   = (float*)carve(256);
  unsigned short* PROJ = QKV;    // alias: q/k/v slots dead once aggregate done
  if (off > ws_size) return;     // insufficient workspace: fail loudly

  // weights -> bf16 transposed [col][row] ("BT" layout for the GEMM)
  transpose_w_kernel<<<dim3(16,16,8), dim3(32,8), 0, stream>>>(W[0], WT);
  transpose_w_kernel<<<dim3(16,16,8), dim3(32,8), 0, stream>>>(W[1], WT + (size_t)8 * 262144);
  transpose_w_kernel<<<dim3(16,16,8), dim3(32,8), 0, stream>>>(W[2], WT + (size_t)16 * 262144);
  transpose_w_kernel<<<dim3(16,16,3), dim3(32,8), 0, stream>>>(headW, WT + (size_t)24 * 262144);

  size_t out_off = 0;
  for (int s = 0; s < 3; ++s) {
    const int N = Ns[s], E = Es[s];
    const int mt = (N + 127) >> 7;
    const int nb = (N + 1023) / 1024;

    init_x_kernel<<<2048, 256, 0, stream>>>(
        (const float4*)feat[s], (const float4*)emb[s], (const float4*)pos[s],
        (float4*)X, XB, (long long)N * 128);

    // CSR by dst (edge index is constant per stream; built once, used 2x)
    hipMemsetAsync(DEG, 0, (size_t)N * 4, stream);
    hist_kernel<<<(E + 255) / 256, 256, 0, stream>>>(ei[s], E, DEG);
    scan_part_kernel<<<nb, 1024, 0, stream>>>(DEG, N, ROWPTR, BSUMS);
    scan_bsums_kernel<<<1, 64, 0, stream>>>(BSUMS, nb);
    scan_add_kernel<<<nb, 1024, 0, stream>>>(ROWPTR, BSUMS, N);
    hipMemsetAsync(DEG, 0, (size_t)N * 4, stream);
    scatter_kernel<<<(E + 255) / 256, 256, 0, stream>>>(ei[s], E, ROWPTR, DEG, SRCS);

    for (int l = 0; l < 2; ++l) {
      const unsigned short* Wqkv = WT + (size_t)(s * 8 + l * 4) * 262144;
      const unsigned short* Wo   = WT + (size_t)(s * 8 + l * 4 + 3) * 262144;
      const float* bqkv = Bb[s] + (size_t)l * 4 * 512;       // q,k,v biases contiguous
      const float* bo   = Bb[s] + (size_t)(l * 4 + 3) * 512;

      gemm_bt_kernel<1><<<dim3(mt * 12), 256, 0, stream>>>(XB, Wqkv, bqkv, QKV, N, 1536);
      csr_scores_kernel<<<(N + 3) / 4, 256, 0, stream>>>(QKV, SRCS, ROWPTR, N, SC);
      sm_max_partial_kernel<<<256, 256, 0, stream>>>(SC, E, PARTM);
      sm_exp_partial_kernel<<<256, 256, 0, stream>>>(SC, E, PARTM, PARTS);
      sm_final_kernel<1><<<1, 256, 0, stream>>>(PARTS, GINV);
      aggregate_kernel<<<(N + 3) / 4, 256, 0, stream>>>(QKV, SC, GINV, SRCS, ROWPTR, N, AGG);
      gemm_bt_kernel<1><<<dim3(mt * 4), 256, 0, stream>>>(AGG, Wo, bo, PROJ, N, 512);
      ln_kernel<<<(N + 3) / 4, 256, 0, stream>>>(PROJ, G[s] + (size_t)l * 512,
                                                 Bt[s] + (size_t)l * 512, X, XB, N);
    }

    gemm_bt_kernel<0><<<dim3(mt * 4), 256, 0, stream>>>(
        XB, WT + (size_t)(24 + s) * 262144, headB + (size_t)s * 512,
        (float*)d_out + out_off, N, 512);
    out_off += (size_t)N * 512;
  }
}

// Round 7
// 1497.820 us; speedup vs baseline: 1.3033x; 1.0765x over previous
//
#include <hip/hip_runtime.h>

// ---------------------------------------------------------------------------
// SimplicialAttentionTransformer: 3 streams x (embed-add, 2x[QKV gemm,
// CSR-ordered edge scores, GLOBAL softmax over edges, CSR segment-sum,
// proj gemm, LN], head gemm). bf16 MFMA GEMM: 2-phase double-buffered LDS
// (A+B, 64KB), swapped-operand MFMA + permuted-weight storage so each lane
// owns 16 CONSECUTIVE output columns -> fully-coalesced 16B direct stores.
// ---------------------------------------------------------------------------

typedef __attribute__((ext_vector_type(8))) __bf16 bf16x8;
typedef __attribute__((ext_vector_type(4))) float f32x4;
typedef __attribute__((ext_vector_type(8))) unsigned short ushort8v;
typedef __attribute__((ext_vector_type(4))) unsigned short ushort4v;

__device__ __forceinline__ float b2f(unsigned short u) {
  union { unsigned u; float f; } x; x.u = (unsigned)u << 16; return x.f;
}
__device__ __forceinline__ unsigned short f2b(float f) {
  union { float f; unsigned u; } x; x.f = f;
  unsigned r = x.u + 0x7fffu + ((x.u >> 16) & 1u);   // RNE
  return (unsigned short)(r >> 16);
}

// ======================= x = a + b + c (f32 + bf16 copies) =================
__global__ __launch_bounds__(256) void init_x_kernel(
    const float4* __restrict__ a, const float4* __restrict__ b,
    const float4* __restrict__ c, float4* __restrict__ x,
    unsigned short* __restrict__ xb, long long n4)
{
  long long stride = (long long)gridDim.x * 256;
  for (long long i = (long long)blockIdx.x * 256 + threadIdx.x; i < n4; i += stride) {
    float4 av = a[i], bv = b[i], cv = c[i];
    float4 r;
    r.x = av.x + bv.x + cv.x; r.y = av.y + bv.y + cv.y;
    r.z = av.z + bv.z + cv.z; r.w = av.w + bv.w + cv.w;
    x[i] = r;
    ushort4v o; o.x = f2b(r.x); o.y = f2b(r.y); o.z = f2b(r.z); o.w = f2b(r.w);
    *(ushort4v*)(xb + i * 4) = o;
  }
}

// ============== weight transpose fp32[512][512] -> bf16 WT[perm(c)][r] =====
// perm swaps bits [5:4] <-> [3:2] within each 64-col block (involution).
// GEMM then computes C_phys[m][p] = C_orig[m][perm(p)], and the epilogue's
// per-lane fragment (p = 16ni+4t+r) maps to orig cols 16t+4ni+r: consecutive.
__global__ __launch_bounds__(256) void transpose_w_kernel(
    const float* __restrict__ W, unsigned short* __restrict__ WT)
{
  __shared__ float t[32][33];
  const float* src = W + (size_t)blockIdx.z * 262144;
  unsigned short* dst = WT + (size_t)blockIdx.z * 262144;
  int bx = blockIdx.x * 32, by = blockIdx.y * 32;
  int tx = threadIdx.x, ty = threadIdx.y;   // block 32x8
  #pragma unroll
  for (int i = 0; i < 32; i += 8)
    t[ty + i][tx] = src[(size_t)(by + ty + i) * 512 + bx + tx];
  __syncthreads();
  #pragma unroll
  for (int i = 0; i < 32; i += 8) {
    int c = bx + ty + i;
    int p = (c & ~0x3C) | ((c & 0x30) >> 2) | ((c & 0x0C) << 2);
    dst[(size_t)p * 512 + by + tx] = f2b(t[tx][ty + i]);
  }
}

// ========================== bf16 GEMM:  C = A @ WTs^T + bias ===============
// A:[M,512] bf16 row-major, WTs:[Ncols,512] bf16 (column-permuted weights),
// C:[M,Ncols] f32|bf16 in ORIGINAL column order. 128x128 tile, BK=64,
// 4 waves (2x2 of 64x64). 2-phase double-buffered global_load_lds staging
// (XOR-swizzled source, linear LDS dest, swizzled ds_read_b128); stage of
// K-step t+1 issued before compute of t. Swapped-operand MFMA.
__device__ __forceinline__ void stage16(const void* g, void* lds_uniform) {
  __builtin_amdgcn_global_load_lds(
      (const __attribute__((address_space(1))) void*)g,
      (__attribute__((address_space(3))) void*)lds_uniform, 16, 0, 0);
}

template<int OUT_BF16>
__global__ __launch_bounds__(256) void gemm_bt_kernel(
    const unsigned short* __restrict__ A,
    const unsigned short* __restrict__ BT,
    const float* __restrict__ bias,
    void* __restrict__ Cv,
    int M, int Ncols)
{
  constexpr int K = 512;
  // double buffer: buf b at smem + b*16384 (As 8192 | Bs 8192), 64KB total
  __shared__ unsigned short smem[32768];

  // bijective XCD-chunked swizzle (m204): consecutive wgid -> same XCD,
  // consecutive wgid share tm (same A panel) -> per-XCD L2 reuse.
  const int nwg = gridDim.x, orig = blockIdx.x;
  const int xcd = orig & 7, lin = orig >> 3;
  const int q = nwg >> 3, r8 = nwg & 7;
  const int wgid = (xcd < r8 ? xcd * (q + 1) : r8 * (q + 1) + (xcd - r8) * q) + lin;

  const int tiles_n = Ncols >> 7;
  const int tm = wgid / tiles_n;
  const int tn = wgid - tm * tiles_n;
  const int row0 = tm << 7, col0 = tn << 7;
  const int lane = threadIdx.x & 63, wid = threadIdx.x >> 6;
  const int wm = (wid >> 1) << 6, wn = (wid & 1) << 6;

  f32x4 acc[4][4];
  #pragma unroll
  for (int i = 0; i < 4; ++i)
    #pragma unroll
    for (int j = 0; j < 4; ++j) acc[i][j] = (f32x4)0.f;

  // staging plan: 16 segs of 1KB per operand, 4 wave-issues each.
  int srow[4], scsw[4], sseg[4];
  #pragma unroll
  for (int i = 0; i < 4; ++i) {
    int seg = (i << 2) | wid;
    int idx = (seg << 6) | lane;     // row = idx>>3, 16B-chunk = idx&7
    int row = idx >> 3, ch = idx & 7;
    sseg[i] = seg; srow[i] = row; scsw[i] = ch ^ (row & 7);  // pre-swizzled src
  }

  #define STAGE(buf, kb_)                                                      \
    _Pragma("unroll")                                                          \
    for (int i = 0; i < 4; ++i) {                                              \
      int ra = row0 + srow[i]; ra = (ra < M) ? ra : (M - 1);                   \
      stage16(A + (size_t)ra * K + (kb_) + (scsw[i] << 3),                     \
              smem + (buf) * 16384 + (sseg[i] << 9));                          \
      int rb = col0 + srow[i];                                                 \
      stage16(BT + (size_t)rb * K + (kb_) + (scsw[i] << 3),                    \
              smem + (buf) * 16384 + 8192 + (sseg[i] << 9));                   \
    }

  STAGE(0, 0)
  asm volatile("s_waitcnt vmcnt(0)" ::: "memory");
  __syncthreads();

  #pragma unroll
  for (int kt = 0; kt < 8; ++kt) {
    const int cur = kt & 1;
    if (kt < 7) {                      // issue next K-step's stage FIRST
      STAGE(cur ^ 1, (kt + 1) << 6)
    }
    const unsigned short* As = smem + cur * 16384;
    const unsigned short* Bs = As + 8192;
    #pragma unroll
    for (int kk = 0; kk < 2; ++kk) {
      const int kb = (kk << 6) + ((lane >> 4) << 4);   // byte off in 128B row
      bf16x8 af[4], bfr[4];
      #pragma unroll
      for (int mi = 0; mi < 4; ++mi) {
        int r = wm + (mi << 4) + (lane & 15);
        af[mi] = *(const bf16x8*)((const char*)As + (r << 7) + (kb ^ ((r & 7) << 4)));
      }
      #pragma unroll
      for (int ni = 0; ni < 4; ++ni) {
        int r = wn + (ni << 4) + (lane & 15);
        bfr[ni] = *(const bf16x8*)((const char*)Bs + (r << 7) + (kb ^ ((r & 7) << 4)));
      }
      #pragma unroll
      for (int mi = 0; mi < 4; ++mi)
        #pragma unroll
        for (int ni = 0; ni < 4; ++ni)
          acc[mi][ni] = __builtin_amdgcn_mfma_f32_16x16x32_bf16(
              bfr[ni], af[mi], acc[mi][ni], 0, 0, 0);  // swapped: D[n][m]
    }
    // next buffer staged + everyone done reading cur before it's overwritten
    asm volatile("s_waitcnt vmcnt(0)" ::: "memory");
    __syncthreads();
  }
  #undef STAGE

  const int mrow = lane & 15;            // local row within 16-block
  const int t4 = (lane >> 4) << 4;       // 16t: lane's orig-col base {0,16,32,48}
  // lane's 16 outputs = orig cols col0+wn+t4 .. +15 (acc[mi][ni][r] -> 4ni+r)
  float bsv[16];
  #pragma unroll
  for (int ni = 0; ni < 4; ++ni) {
    float4 bv = *(const float4*)(bias + col0 + wn + t4 + (ni << 2));
    bsv[4*ni+0] = bv.x; bsv[4*ni+1] = bv.y; bsv[4*ni+2] = bv.z; bsv[4*ni+3] = bv.w;
  }

  if (OUT_BF16) {
    unsigned short* C = (unsigned short*)Cv;
    #pragma unroll
    for (int mi = 0; mi < 4; ++mi) {
      int rowg = row0 + wm + (mi << 4) + mrow;
      if (rowg < M) {
        ushort8v o0, o1;
        #pragma unroll
        for (int r = 0; r < 4; ++r) {
          o0[r]     = f2b(acc[mi][0][r] + bsv[r]);
          o0[4 + r] = f2b(acc[mi][1][r] + bsv[4 + r]);
          o1[r]     = f2b(acc[mi][2][r] + bsv[8 + r]);
          o1[4 + r] = f2b(acc[mi][3][r] + bsv[12 + r]);
        }
        unsigned short* cp = C + (size_t)rowg * Ncols + col0 + wn + t4;
        *(ushort8v*)cp = o0;
        *(ushort8v*)(cp + 8) = o1;
      }
    }
  } else {
    float* C = (float*)Cv;
    #pragma unroll
    for (int mi = 0; mi < 4; ++mi) {
      int rowg = row0 + wm + (mi << 4) + mrow;
      if (rowg < M) {
        float* cp = C + (size_t)rowg * Ncols + col0 + wn + t4;
        #pragma unroll
        for (int ni = 0; ni < 4; ++ni) {
          float4 v;
          v.x = acc[mi][ni][0] + bsv[4*ni+0];
          v.y = acc[mi][ni][1] + bsv[4*ni+1];
          v.z = acc[mi][ni][2] + bsv[4*ni+2];
          v.w = acc[mi][ni][3] + bsv[4*ni+3];
          *(float4*)(cp + (ni << 2)) = v;
        }
      }
    }
  }
}

// ====== CSR-ordered edge scores: sc[i][h] = q[n] . k[src(i)] / 8 ===========
// One wave per dst node n: q[n] loaded once to regs, k gathered per in-edge.
// sc stored at CSR position i (softmax is global over edges -> order-free).
__global__ __launch_bounds__(256) void csr_scores_kernel(
    const unsigned short* __restrict__ qkv, const int* __restrict__ srcs,
    const int* __restrict__ rowptr, int N, float* __restrict__ sc)
{
  int wid = threadIdx.x >> 6, lane = threadIdx.x & 63;
  int n = (blockIdx.x << 2) | wid;
  if (n >= N) return;
  int beg = rowptr[n], end = rowptr[n + 1];
  if (beg == end) return;
  ushort8v qv = *(const ushort8v*)(qkv + (size_t)n * 1536 + (lane << 3));
  float qf[8];
  #pragma unroll
  for (int j = 0; j < 8; ++j) qf[j] = b2f(qv[j]);
  int i = beg;
  for (; i + 2 <= end; i += 2) {       // 2-edge ILP
    int s0 = srcs[i], s1 = srcs[i + 1];
    ushort8v k0 = *(const ushort8v*)(qkv + (size_t)s0 * 1536 + 512 + (lane << 3));
    ushort8v k1 = *(const ushort8v*)(qkv + (size_t)s1 * 1536 + 512 + (lane << 3));
    float p0 = 0.f, p1 = 0.f;
    #pragma unroll
    for (int j = 0; j < 8; ++j) { p0 += qf[j] * b2f(k0[j]); p1 += qf[j] * b2f(k1[j]); }
    p0 += __shfl_xor(p0, 1); p1 += __shfl_xor(p1, 1);
    p0 += __shfl_xor(p0, 2); p1 += __shfl_xor(p1, 2);
    p0 += __shfl_xor(p0, 4); p1 += __shfl_xor(p1, 4);
    if (!(lane & 7)) {
      sc[(size_t)i * 8 + (lane >> 3)] = p0 * 0.125f;
      sc[(size_t)(i + 1) * 8 + (lane >> 3)] = p1 * 0.125f;
    }
  }
  if (i < end) {
    int s0 = srcs[i];
    ushort8v k0 = *(const ushort8v*)(qkv + (size_t)s0 * 1536 + 512 + (lane << 3));
    float p0 = 0.f;
    #pragma unroll
    for (int j = 0; j < 8; ++j) p0 += qf[j] * b2f(k0[j]);
    p0 += __shfl_xor(p0, 1);
    p0 += __shfl_xor(p0, 2);
    p0 += __shfl_xor(p0, 4);
    if (!(lane & 7)) sc[(size_t)i * 8 + (lane >> 3)] = p0 * 0.125f;
  }
}

// ==================== global softmax over edge axis (per head) ==============
template<int OP>   // 0 = max, 1 = sum
__device__ __forceinline__ void reduce8_block(float (&v)[8], float* red) {
  int lane = threadIdx.x & 63, wid = threadIdx.x >> 6;
  #pragma unroll
  for (int h = 0; h < 8; ++h)
    #pragma unroll
    for (int off = 1; off < 64; off <<= 1) {
      float o = __shfl_xor(v[h], off);
      v[h] = OP ? (v[h] + o) : fmaxf(v[h], o);
    }
  if (lane == 0) {
    #pragma unroll
    for (int h = 0; h < 8; ++h) red[h * 4 + wid] = v[h];
  }
  __syncthreads();
  if (threadIdx.x == 0) {
    #pragma unroll
    for (int h = 0; h < 8; ++h) {
      float r = red[h * 4];
      #pragma unroll
      for (int w = 1; w < 4; ++w)
        r = OP ? (r + red[h * 4 + w]) : fmaxf(r, red[h * 4 + w]);
      v[h] = r;
    }
  }
}

__global__ __launch_bounds__(256) void sm_max_partial_kernel(
    const float* __restrict__ sc, int E, float* __restrict__ part)
{
  __shared__ float red[32];
  float v[8];
  #pragma unroll
  for (int h = 0; h < 8; ++h) v[h] = -1e30f;
  int stride = gridDim.x * 256;
  for (int e = blockIdx.x * 256 + threadIdx.x; e < E; e += stride) {
    #pragma unroll
    for (int h = 0; h < 8; ++h) v[h] = fmaxf(v[h], sc[(size_t)e * 8 + h]);
  }
  reduce8_block<0>(v, red);
  if (threadIdx.x == 0) {
    #pragma unroll
    for (int h = 0; h < 8; ++h) part[blockIdx.x * 8 + h] = v[h];
  }
}

// exp pass with the global-max reduction fused in (reads 256-block partials)
__global__ __launch_bounds__(256) void sm_exp_partial_kernel(
    float* __restrict__ sc, int E, const float* __restrict__ partm,
    float* __restrict__ parts)
{
  __shared__ float red[32];
  __shared__ float gmx[8];
  float v[8];
  #pragma unroll
  for (int h = 0; h < 8; ++h) v[h] = partm[threadIdx.x * 8 + h];
  reduce8_block<0>(v, red);
  if (threadIdx.x == 0) {
    #pragma unroll
    for (int h = 0; h < 8; ++h) gmx[h] = v[h];
  }
  __syncthreads();
  float gm[8];
  #pragma unroll
  for (int h = 0; h < 8; ++h) { gm[h] = gmx[h]; v[h] = 0.f; }
  int stride = gridDim.x * 256;
  for (int e = blockIdx.x * 256 + threadIdx.x; e < E; e += stride) {
    #pragma unroll
    for (int h = 0; h < 8; ++h) {
      float w = __expf(sc[(size_t)e * 8 + h] - gm[h]);
      sc[(size_t)e * 8 + h] = w;           // in-place exp
      v[h] += w;
    }
  }
  reduce8_block<1>(v, red);
  if (threadIdx.x == 0) {
    #pragma unroll
    for (int h = 0; h < 8; ++h) parts[blockIdx.x * 8 + h] = v[h];
  }
}

template<int OP>   // 1: out = 1/sum
__global__ __launch_bounds__(256) void sm_final_kernel(
    const float* __restrict__ part, float* __restrict__ out)
{
  __shared__ float red[32];
  float v[8];
  #pragma unroll
  for (int h = 0; h < 8; ++h) v[h] = part[threadIdx.x * 8 + h];
  reduce8_block<OP>(v, red);
  if (threadIdx.x == 0) {
    #pragma unroll
    for (int h = 0; h < 8; ++h) out[h] = OP ? (1.0f / v[h]) : v[h];
  }
}

// =============================== CSR build ==================================
__global__ __launch_bounds__(256) void hist_kernel(
    const int* __restrict__ ei, int E, int* __restrict__ deg)
{
  int e = blockIdx.x * 256 + threadIdx.x;
  if (e < E) atomicAdd(&deg[ei[E + e]], 1);
}

// 3-kernel scan: per-block scan (shfl), scan of block sums, offset add
__global__ __launch_bounds__(1024) void scan_part_kernel(
    const int* __restrict__ deg, int N, int* __restrict__ rowptr,
    int* __restrict__ bsums)
{
  __shared__ int wsum[16];
  int i = blockIdx.x * 1024 + threadIdx.x;
  int lane = threadIdx.x & 63, wid = threadIdx.x >> 6;
  int sv = (i < N) ? deg[i] : 0;
  #pragma unroll
  for (int off = 1; off < 64; off <<= 1) {
    int t = __shfl_up(sv, off);
    if (lane >= off) sv += t;
  }
  if (lane == 63) wsum[wid] = sv;
  __syncthreads();
  if (threadIdx.x < 16) {
    int ws = wsum[threadIdx.x];
    #pragma unroll
    for (int off = 1; off < 16; off <<= 1) {
      int t = __shfl_up(ws, off);
      if (threadIdx.x >= off) ws += t;
    }
    wsum[threadIdx.x] = ws;
  }
  __syncthreads();
  if (wid > 0) sv += wsum[wid - 1];
  if (i < N) rowptr[i + 1] = sv;
  if (threadIdx.x == 1023) bsums[blockIdx.x] = sv;
}

__global__ __launch_bounds__(64) void scan_bsums_kernel(int* bsums, int nb)
{
  int lane = threadIdx.x;
  int v = (lane < nb) ? bsums[lane] : 0;
  #pragma unroll
  for (int off = 1; off < 64; off <<= 1) {
    int t = __shfl_up(v, off);
    if (lane >= off) v += t;
  }
  int ex = __shfl_up(v, 1);
  if (lane == 0) ex = 0;
  if (lane < nb) bsums[lane] = ex;     // exclusive offsets, in place
}

__global__ __launch_bounds__(1024) void scan_add_kernel(
    int* __restrict__ rowptr, const int* __restrict__ bsums, int N)
{
  int i = blockIdx.x * 1024 + threadIdx.x;
  if (i == 0) rowptr[0] = 0;
  if (i < N && blockIdx.x > 0) rowptr[i + 1] += bsums[blockIdx.x];
}

// scatter: store SOURCE id directly at CSR slot (scores/aggregate need only src)
__global__ __launch_bounds__(256) void scatter_kernel(
    const int* __restrict__ ei, int E, const int* __restrict__ rowptr,
    int* __restrict__ cur, int* __restrict__ srcs)
{
  int e = blockIdx.x * 256 + threadIdx.x;
  if (e < E) {
    int dst = ei[E + e];
    int pos = atomicAdd(&cur[dst], 1);
    srcs[rowptr[dst] + pos] = ei[e];
  }
}

// ====== aggregate: agg[n] = sum_{i in CSR(n)} w[i,h] * v[srcs[i]] ==========
__global__ __launch_bounds__(256) void aggregate_kernel(
    const unsigned short* __restrict__ qkv, const float* __restrict__ wexp,
    const float* __restrict__ ginv, const int* __restrict__ srcs,
    const int* __restrict__ rowptr, int N, unsigned short* __restrict__ agg)
{
  int wid = threadIdx.x >> 6, lane = threadIdx.x & 63;
  int n = (blockIdx.x << 2) | wid;
  if (n >= N) return;
  int beg = rowptr[n], end = rowptr[n + 1];
  int h = lane >> 3;
  float inv = ginv[h];
  float acc[8] = {0.f,0.f,0.f,0.f,0.f,0.f,0.f,0.f};
  int i = beg;
  for (; i + 2 <= end; i += 2) {       // 2-edge ILP
    int s0 = srcs[i], s1 = srcs[i + 1];
    float w0 = wexp[(size_t)i * 8 + h] * inv;
    float w1 = wexp[(size_t)(i + 1) * 8 + h] * inv;
    ushort8v v0 = *(const ushort8v*)(qkv + (size_t)s0 * 1536 + 1024 + (lane << 3));
    ushort8v v1 = *(const ushort8v*)(qkv + (size_t)s1 * 1536 + 1024 + (lane << 3));
    #pragma unroll
    for (int j = 0; j < 8; ++j) acc[j] += w0 * b2f(v0[j]) + w1 * b2f(v1[j]);
  }
  if (i < end) {
    int s0 = srcs[i];
    float w0 = wexp[(size_t)i * 8 + h] * inv;
    ushort8v v0 = *(const ushort8v*)(qkv + (size_t)s0 * 1536 + 1024 + (lane << 3));
    #pragma unroll
    for (int j = 0; j < 8; ++j) acc[j] += w0 * b2f(v0[j]);
  }
  ushort8v o;
  #pragma unroll
  for (int j = 0; j < 8; ++j) o[j] = f2b(acc[j]);
  *(ushort8v*)(agg + (size_t)n * 512 + (lane << 3)) = o;
}

// ====================== LN(proj + resid)*g + bt  (wave/row) =================
__global__ __launch_bounds__(256) void ln_kernel(
    const unsigned short* __restrict__ proj, const float* __restrict__ g,
    const float* __restrict__ bt, float* __restrict__ x,
    unsigned short* __restrict__ xb, int N)
{
  int wid = threadIdx.x >> 6, lane = threadIdx.x & 63;
  int n = (blockIdx.x << 2) | wid;
  if (n >= N) return;
  size_t base = (size_t)n * 512 + (lane << 3);
  ushort8v pv = *(const ushort8v*)(proj + base);
  const float4* xp = (const float4*)(x + base);
  float4 x0 = xp[0], x1 = xp[1];
  float y[8] = {b2f(pv[0]) + x0.x, b2f(pv[1]) + x0.y, b2f(pv[2]) + x0.z,
                b2f(pv[3]) + x0.w, b2f(pv[4]) + x1.x, b2f(pv[5]) + x1.y,
                b2f(pv[6]) + x1.z, b2f(pv[7]) + x1.w};
  float s = 0.f;
  #pragma unroll
  for (int j = 0; j < 8; ++j) s += y[j];
  #pragma unroll
  for (int off = 1; off < 64; off <<= 1) s += __shfl_xor(s, off);
  float mean = s * (1.f / 512.f);
  float vs = 0.f;
  #pragma unroll
  for (int j = 0; j < 8; ++j) { float d = y[j] - mean; vs += d * d; }
  #pragma unroll
  for (int off = 1; off < 64; off <<= 1) vs += __shfl_xor(vs, off);
  float rstd = rsqrtf(vs * (1.f / 512.f) + 1e-5f);
  int gi = lane << 3;
  float o[8];
  #pragma unroll
  for (int j = 0; j < 8; ++j) o[j] = (y[j] - mean) * rstd * g[gi + j] + bt[gi + j];
  float4 r0 = {o[0], o[1], o[2], o[3]}, r1 = {o[4], o[5], o[6], o[7]};
  *(float4*)(x + base) = r0;
  *(float4*)(x + base + 4) = r1;
  ushort8v ob;
  #pragma unroll
  for (int j = 0; j < 8; ++j) ob[j] = f2b(o[j]);
  *(ushort8v*)(xb + base) = ob;
}

// ================================ driver ====================================
extern "C" void kernel_launch(void* const* d_in, const int* in_sizes, int n_in,
                              void* d_out, int out_size, void* d_ws, size_t ws_size,
                              hipStream_t stream)
{
  (void)n_in; (void)out_size;
  const float* feat[3] = {(const float*)d_in[0], (const float*)d_in[1], (const float*)d_in[2]};
  const float* emb[3]  = {(const float*)d_in[3], (const float*)d_in[4], (const float*)d_in[5]};
  const float* pos[3]  = {(const float*)d_in[6], (const float*)d_in[7], (const float*)d_in[8]};
  const float* W[3]  = {(const float*)d_in[9],  (const float*)d_in[13], (const float*)d_in[17]};
  const float* Bb[3] = {(const float*)d_in[10], (const float*)d_in[14], (const float*)d_in[18]};
  const float* G[3]  = {(const float*)d_in[11], (const float*)d_in[15], (const float*)d_in[19]};
  const float* Bt[3] = {(const float*)d_in[12], (const float*)d_in[16], (const float*)d_in[20]};
  const float* headW = (const float*)d_in[21];
  const float* headB = (const float*)d_in[22];
  const int* ei[3] = {(const int*)d_in[23], (const int*)d_in[24], (const int*)d_in[25]};

  int Ns[3], Es[3];
  for (int s = 0; s < 3; ++s) { Ns[s] = in_sizes[s] / 512; Es[s] = in_sizes[23 + s] / 2; }
  int NMAX = Ns[0], EMAX = Es[0];
  for (int s = 1; s < 3; ++s) { if (Ns[s] > NMAX) NMAX = Ns[s]; if (Es[s] > EMAX) EMAX = Es[s]; }

  char* base = (char*)d_ws;
  size_t off = 0;
  auto carve = [&](size_t bytes) -> char* {
    char* r = base + off;
    off += (bytes + 255) & ~(size_t)255;
    return r;
  };
  unsigned short* WT  = (unsigned short*)carve((size_t)27 * 262144 * 2);
  float*          X   = (float*)carve((size_t)NMAX * 512 * 4);
  unsigned short* XB  = (unsigned short*)carve((size_t)NMAX * 512 * 2);
  unsigned short* QKV = (unsigned short*)carve((size_t)NMAX * 1536 * 2);
  float*          SC  = (float*)carve((size_t)EMAX * 8 * 4);
  unsigned short* AGG = (unsigned short*)carve((size_t)NMAX * 512 * 2);
  int*   ROWPTR = (int*)carve((size_t)(NMAX + 1) * 4);
  int*   DEG    = (int*)carve((size_t)NMAX * 4);
  int*   SRCS   = (int*)carve((size_t)EMAX * 4);
  int*   BSUMS  = (int*)carve(64 * 4);
  float* PARTM  = (float*)carve(256 * 8 * 4);
  float* PARTS  = (float*)carve(256 * 8 * 4);
  float* GINV   = (float*)carve(256);
  unsigned short* PROJ = QKV;    // alias: q/k/v slots dead once aggregate done
  if (off > ws_size) return;     // insufficient workspace: fail loudly

  // weights -> bf16 transposed + column-permuted ("WTs" layout for the GEMM)
  transpose_w_kernel<<<dim3(16,16,8), dim3(32,8), 0, stream>>>(W[0], WT);
  transpose_w_kernel<<<dim3(16,16,8), dim3(32,8), 0, stream>>>(W[1], WT + (size_t)8 * 262144);
  transpose_w_kernel<<<dim3(16,16,8), dim3(32,8), 0, stream>>>(W[2], WT + (size_t)16 * 262144);
  transpose_w_kernel<<<dim3(16,16,3), dim3(32,8), 0, stream>>>(headW, WT + (size_t)24 * 262144);

  size_t out_off = 0;
  for (int s = 0; s < 3; ++s) {
    const int N = Ns[s], E = Es[s];
    const int mt = (N + 127) >> 7;
    const int nb = (N + 1023) / 1024;

    init_x_kernel<<<2048, 256, 0, stream>>>(
        (const float4*)feat[s], (const float4*)emb[s], (const float4*)pos[s],
        (float4*)X, XB, (long long)N * 128);

    // CSR by dst (edge index is constant per stream; built once, used 2x)
    hipMemsetAsync(DEG, 0, (size_t)N * 4, stream);
    hist_kernel<<<(E + 255) / 256, 256, 0, stream>>>(ei[s], E, DEG);
    scan_part_kernel<<<nb, 1024, 0, stream>>>(DEG, N, ROWPTR, BSUMS);
    scan_bsums_kernel<<<1, 64, 0, stream>>>(BSUMS, nb);
    scan_add_kernel<<<nb, 1024, 0, stream>>>(ROWPTR, BSUMS, N);
    hipMemsetAsync(DEG, 0, (size_t)N * 4, stream);
    scatter_kernel<<<(E + 255) / 256, 256, 0, stream>>>(ei[s], E, ROWPTR, DEG, SRCS);

    for (int l = 0; l < 2; ++l) {
      const unsigned short* Wqkv = WT + (size_t)(s * 8 + l * 4) * 262144;
      const unsigned short* Wo   = WT + (size_t)(s * 8 + l * 4 + 3) * 262144;
      const float* bqkv = Bb[s] + (size_t)l * 4 * 512;       // q,k,v biases contiguous
      const float* bo   = Bb[s] + (size_t)(l * 4 + 3) * 512;

      gemm_bt_kernel<1><<<dim3(mt * 12), 256, 0, stream>>>(XB, Wqkv, bqkv, QKV, N, 1536);
      csr_scores_kernel<<<(N + 3) / 4, 256, 0, stream>>>(QKV, SRCS, ROWPTR, N, SC);
      sm_max_partial_kernel<<<256, 256, 0, stream>>>(SC, E, PARTM);
      sm_exp_partial_kernel<<<256, 256, 0, stream>>>(SC, E, PARTM, PARTS);
      sm_final_kernel<1><<<1, 256, 0, stream>>>(PARTS, GINV);
      aggregate_kernel<<<(N + 3) / 4, 256, 0, stream>>>(QKV, SC, GINV, SRCS, ROWPTR, N, AGG);
      gemm_bt_kernel<1><<<dim3(mt * 4), 256, 0, stream>>>(AGG, Wo, bo, PROJ, N, 512);
      ln_kernel<<<(N + 3) / 4, 256, 0, stream>>>(PROJ, G[s] + (size_t)l * 512,
                                                 Bt[s] + (size_t)l * 512, X, XB, N);
    }

    gemm_bt_kernel<0><<<dim3(mt * 4), 256, 0, stream>>>(
        XB, WT + (size_t)(24 + s) * 262144, headB + (size_t)s * 512,
        (float*)d_out + out_off, N, 512);
    out_off += (size_t)N * 512;
  }
}

// Round 8
// 1496.250 us; speedup vs baseline: 1.3047x; 1.0010x over previous
//
#include <hip/hip_runtime.h>

// ---------------------------------------------------------------------------
// SimplicialAttentionTransformer: 3 streams x (embed-add, 2x[QKV gemm,
// CSR-ordered edge scores, GLOBAL softmax over edges, CSR segment-sum,
// proj gemm, LN], head gemm). bf16 MFMA GEMM: 256x256 tile, 8 waves
// (wave-tile 128x64), 4-phase-per-K-tile schedule, double-buffered
// global_load_lds staging (XOR-swizzled source), raw s_barrier phases
// (vmcnt NOT drained inside a tile), setprio around MFMA clusters,
// swapped-operand MFMA + permuted weights -> 16 consecutive cols/lane.
// ---------------------------------------------------------------------------

typedef __attribute__((ext_vector_type(8))) __bf16 bf16x8;
typedef __attribute__((ext_vector_type(4))) float f32x4;
typedef __attribute__((ext_vector_type(8))) unsigned short ushort8v;
typedef __attribute__((ext_vector_type(4))) unsigned short ushort4v;

__device__ __forceinline__ float b2f(unsigned short u) {
  union { unsigned u; float f; } x; x.u = (unsigned)u << 16; return x.f;
}
__device__ __forceinline__ unsigned short f2b(float f) {
  union { float f; unsigned u; } x; x.f = f;
  unsigned r = x.u + 0x7fffu + ((x.u >> 16) & 1u);   // RNE
  return (unsigned short)(r >> 16);
}

// ======================= x = a + b + c (f32 + bf16 copies) =================
__global__ __launch_bounds__(256) void init_x_kernel(
    const float4* __restrict__ a, const float4* __restrict__ b,
    const float4* __restrict__ c, float4* __restrict__ x,
    unsigned short* __restrict__ xb, long long n4)
{
  long long stride = (long long)gridDim.x * 256;
  for (long long i = (long long)blockIdx.x * 256 + threadIdx.x; i < n4; i += stride) {
    float4 av = a[i], bv = b[i], cv = c[i];
    float4 r;
    r.x = av.x + bv.x + cv.x; r.y = av.y + bv.y + cv.y;
    r.z = av.z + bv.z + cv.z; r.w = av.w + bv.w + cv.w;
    x[i] = r;
    ushort4v o; o.x = f2b(r.x); o.y = f2b(r.y); o.z = f2b(r.z); o.w = f2b(r.w);
    *(ushort4v*)(xb + i * 4) = o;
  }
}

// ============== weight transpose fp32[512][512] -> bf16 WT[perm(c)][r] =====
// perm swaps bits [5:4] <-> [3:2] within each 64-col block (involution).
__global__ __launch_bounds__(256) void transpose_w_kernel(
    const float* __restrict__ W, unsigned short* __restrict__ WT)
{
  __shared__ float t[32][33];
  const float* src = W + (size_t)blockIdx.z * 262144;
  unsigned short* dst = WT + (size_t)blockIdx.z * 262144;
  int bx = blockIdx.x * 32, by = blockIdx.y * 32;
  int tx = threadIdx.x, ty = threadIdx.y;   // block 32x8
  #pragma unroll
  for (int i = 0; i < 32; i += 8)
    t[ty + i][tx] = src[(size_t)(by + ty + i) * 512 + bx + tx];
  __syncthreads();
  #pragma unroll
  for (int i = 0; i < 32; i += 8) {
    int c = bx + ty + i;
    int p = (c & ~0x3C) | ((c & 0x30) >> 2) | ((c & 0x0C) << 2);
    dst[(size_t)p * 512 + by + tx] = f2b(t[tx][ty + i]);
  }
}

// ========================== bf16 GEMM:  C = A @ WTs^T + bias ===============
__device__ __forceinline__ void stage16(const void* g, void* lds_uniform) {
  __builtin_amdgcn_global_load_lds(
      (const __attribute__((address_space(1))) void*)g,
      (__attribute__((address_space(3))) void*)lds_uniform, 16, 0, 0);
}

template<int OUT_BF16>
__global__ __launch_bounds__(512, 2) void gemm_bt_kernel(
    const unsigned short* __restrict__ A,
    const unsigned short* __restrict__ BT,
    const float* __restrict__ bias,
    void* __restrict__ Cv,
    int M, int Ncols)
{
  constexpr int K = 512;
  // 128KB: buf b at shorts [b*32768, +16384)=A(256x64), [+16384,+32768)=B
  __shared__ unsigned short smem[65536];

  // bijective XCD-chunked swizzle (m204)
  const int nwg = gridDim.x, orig = blockIdx.x;
  const int xcd = orig & 7, lin = orig >> 3;
  const int q = nwg >> 3, r8 = nwg & 7;
  const int wgid = (xcd < r8 ? xcd * (q + 1) : r8 * (q + 1) + (xcd - r8) * q) + lin;

  const int tiles_n = Ncols >> 8;
  const int tm = wgid / tiles_n;
  const int tn = wgid - tm * tiles_n;
  const int row0 = tm << 8, col0 = tn << 8;
  const int lane = threadIdx.x & 63, wid = threadIdx.x >> 6;
  const int wr = (wid >> 2) << 7;   // M-half: 0 / 128
  const int wc = (wid & 3) << 6;    // N-quarter: 0/64/128/192

  f32x4 acc[8][4];
  #pragma unroll
  for (int i = 0; i < 8; ++i)
    #pragma unroll
    for (int j = 0; j < 4; ++j) acc[i][j] = (f32x4)0.f;

  // staging plan: 32 segs of 1KB per operand; wave owns segs (i<<3)|wid.
  int srow[4], scsw[4], sseg[4];
  #pragma unroll
  for (int i = 0; i < 4; ++i) {
    int seg = (i << 3) | wid;
    int idx = (seg << 6) | lane;     // row = idx>>3 (0..255), chunk = idx&7
    int row = idx >> 3, ch = idx & 7;
    sseg[i] = seg; srow[i] = row; scsw[i] = ch ^ (row & 7);  // pre-swizzled src
  }

  #define STG_PAIR(buf, kb_, i)                                               \
    { int ra = row0 + srow[i]; ra = (ra < M) ? ra : (M - 1);                  \
      stage16(A + (size_t)ra * K + (kb_) + (scsw[i] << 3),                    \
              smem + (buf) * 32768 + (sseg[i] << 9));                         \
      int rb = col0 + srow[i];                                                \
      stage16(BT + (size_t)rb * K + (kb_) + (scsw[i] << 3),                   \
              smem + (buf) * 32768 + 16384 + (sseg[i] << 9)); }

  STG_PAIR(0, 0, 0) STG_PAIR(0, 0, 1) STG_PAIR(0, 0, 2) STG_PAIR(0, 0, 3)
  __syncthreads();

  const int lm = lane & 15;
  const int kbl = (lane >> 4) << 4;

  #pragma unroll
  for (int kt = 0; kt < 8; ++kt) {
    const int cur = kt & 1, nxt = cur ^ 1, kb1 = (kt + 1) << 6;
    const char* Asb = (const char*)(smem + cur * 32768);
    const char* Bsb = Asb + 32768;   // bytes

    auto rdA = [&](int mi, int kk) -> bf16x8 {
      int r = wr + (mi << 4) + lm;
      int kb = (kk << 6) + kbl;
      return *(const bf16x8*)(Asb + (r << 7) + (kb ^ ((r & 7) << 4)));
    };
    auto rdB = [&](int ni, int kk) -> bf16x8 {
      int r = wc + (ni << 4) + lm;
      int kb = (kk << 6) + kbl;
      return *(const bf16x8*)(Bsb + (r << 7) + (kb ^ ((r & 7) << 4)));
    };

    bf16x8 av[4], bv[4];

    // ---- phase 0: frags (mi 0-3, kk0) + B(kk0); stage pairs 0,1 of t+1
    #pragma unroll
    for (int i = 0; i < 4; ++i) { av[i] = rdA(i, 0); bv[i] = rdB(i, 0); }
    if (kt < 7) { STG_PAIR(nxt, kb1, 0) STG_PAIR(nxt, kb1, 1) }
    __builtin_amdgcn_s_barrier();
    __builtin_amdgcn_s_setprio(1);
    #pragma unroll
    for (int mi = 0; mi < 4; ++mi)
      #pragma unroll
      for (int ni = 0; ni < 4; ++ni)
        acc[mi][ni] = __builtin_amdgcn_mfma_f32_16x16x32_bf16(
            bv[ni], av[mi], acc[mi][ni], 0, 0, 0);
    __builtin_amdgcn_s_setprio(0);
    __builtin_amdgcn_s_barrier();

    // ---- phase 1: frags (mi 4-7, kk0); stage pairs 2,3 of t+1
    #pragma unroll
    for (int i = 0; i < 4; ++i) av[i] = rdA(4 + i, 0);
    if (kt < 7) { STG_PAIR(nxt, kb1, 2) STG_PAIR(nxt, kb1, 3) }
    __builtin_amdgcn_s_barrier();
    __builtin_amdgcn_s_setprio(1);
    #pragma unroll
    for (int mi = 0; mi < 4; ++mi)
      #pragma unroll
      for (int ni = 0; ni < 4; ++ni)
        acc[4 + mi][ni] = __builtin_amdgcn_mfma_f32_16x16x32_bf16(
            bv[ni], av[mi], acc[4 + mi][ni], 0, 0, 0);
    __builtin_amdgcn_s_setprio(0);
    __builtin_amdgcn_s_barrier();

    // ---- phase 2: frags (mi 0-3, kk1) + B(kk1)
    #pragma unroll
    for (int i = 0; i < 4; ++i) { av[i] = rdA(i, 1); bv[i] = rdB(i, 1); }
    __builtin_amdgcn_s_barrier();
    __builtin_amdgcn_s_setprio(1);
    #pragma unroll
    for (int mi = 0; mi < 4; ++mi)
      #pragma unroll
      for (int ni = 0; ni < 4; ++ni)
        acc[mi][ni] = __builtin_amdgcn_mfma_f32_16x16x32_bf16(
            bv[ni], av[mi], acc[mi][ni], 0, 0, 0);
    __builtin_amdgcn_s_setprio(0);
    __builtin_amdgcn_s_barrier();

    // ---- phase 3: frags (mi 4-7, kk1)
    #pragma unroll
    for (int i = 0; i < 4; ++i) av[i] = rdA(4 + i, 1);
    __builtin_amdgcn_s_barrier();
    __builtin_amdgcn_s_setprio(1);
    #pragma unroll
    for (int mi = 0; mi < 4; ++mi)
      #pragma unroll
      for (int ni = 0; ni < 4; ++ni)
        acc[4 + mi][ni] = __builtin_amdgcn_mfma_f32_16x16x32_bf16(
            bv[ni], av[mi], acc[4 + mi][ni], 0, 0, 0);
    __builtin_amdgcn_s_setprio(0);

    // K-tile boundary: drain (t+1 landed; everyone done reading cur)
    __syncthreads();
  }
  #undef STG_PAIR

  const int mrow = lane & 15;
  const int t4 = (lane >> 4) << 4;       // lane's orig-col base within 64
  float bsv[16];
  #pragma unroll
  for (int ni = 0; ni < 4; ++ni) {
    float4 bvv = *(const float4*)(bias + col0 + wc + t4 + (ni << 2));
    bsv[4*ni+0] = bvv.x; bsv[4*ni+1] = bvv.y; bsv[4*ni+2] = bvv.z; bsv[4*ni+3] = bvv.w;
  }

  if (OUT_BF16) {
    unsigned short* C = (unsigned short*)Cv;
    #pragma unroll
    for (int mi = 0; mi < 8; ++mi) {
      int rowg = row0 + wr + (mi << 4) + mrow;
      if (rowg < M) {
        ushort8v o0, o1;
        #pragma unroll
        for (int r = 0; r < 4; ++r) {
          o0[r]     = f2b(acc[mi][0][r] + bsv[r]);
          o0[4 + r] = f2b(acc[mi][1][r] + bsv[4 + r]);
          o1[r]     = f2b(acc[mi][2][r] + bsv[8 + r]);
          o1[4 + r] = f2b(acc[mi][3][r] + bsv[12 + r]);
        }
        unsigned short* cp = C + (size_t)rowg * Ncols + col0 + wc + t4;
        *(ushort8v*)cp = o0;
        *(ushort8v*)(cp + 8) = o1;
      }
    }
  } else {
    float* C = (float*)Cv;
    #pragma unroll
    for (int mi = 0; mi < 8; ++mi) {
      int rowg = row0 + wr + (mi << 4) + mrow;
      if (rowg < M) {
        float* cp = C + (size_t)rowg * Ncols + col0 + wc + t4;
        #pragma unroll
        for (int ni = 0; ni < 4; ++ni) {
          float4 v;
          v.x = acc[mi][ni][0] + bsv[4*ni+0];
          v.y = acc[mi][ni][1] + bsv[4*ni+1];
          v.z = acc[mi][ni][2] + bsv[4*ni+2];
          v.w = acc[mi][ni][3] + bsv[4*ni+3];
          *(float4*)(cp + (ni << 2)) = v;
        }
      }
    }
  }
}

// ====== CSR-ordered edge scores: sc[i][h] = q[n] . k[src(i)] / 8 ===========
__global__ __launch_bounds__(256) void csr_scores_kernel(
    const unsigned short* __restrict__ qkv, const int* __restrict__ srcs,
    const int* __restrict__ rowptr, int N, float* __restrict__ sc)
{
  int wid = threadIdx.x >> 6, lane = threadIdx.x & 63;
  int n = (blockIdx.x << 2) | wid;
  if (n >= N) return;
  int beg = rowptr[n], end = rowptr[n + 1];
  if (beg == end) return;
  ushort8v qv = *(const ushort8v*)(qkv + (size_t)n * 1536 + (lane << 3));
  float qf[8];
  #pragma unroll
  for (int j = 0; j < 8; ++j) qf[j] = b2f(qv[j]);
  int i = beg;
  for (; i + 2 <= end; i += 2) {       // 2-edge ILP
    int s0 = srcs[i], s1 = srcs[i + 1];
    ushort8v k0 = *(const ushort8v*)(qkv + (size_t)s0 * 1536 + 512 + (lane << 3));
    ushort8v k1 = *(const ushort8v*)(qkv + (size_t)s1 * 1536 + 512 + (lane << 3));
    float p0 = 0.f, p1 = 0.f;
    #pragma unroll
    for (int j = 0; j < 8; ++j) { p0 += qf[j] * b2f(k0[j]); p1 += qf[j] * b2f(k1[j]); }
    p0 += __shfl_xor(p0, 1); p1 += __shfl_xor(p1, 1);
    p0 += __shfl_xor(p0, 2); p1 += __shfl_xor(p1, 2);
    p0 += __shfl_xor(p0, 4); p1 += __shfl_xor(p1, 4);
    if (!(lane & 7)) {
      sc[(size_t)i * 8 + (lane >> 3)] = p0 * 0.125f;
      sc[(size_t)(i + 1) * 8 + (lane >> 3)] = p1 * 0.125f;
    }
  }
  if (i < end) {
    int s0 = srcs[i];
    ushort8v k0 = *(const ushort8v*)(qkv + (size_t)s0 * 1536 + 512 + (lane << 3));
    float p0 = 0.f;
    #pragma unroll
    for (int j = 0; j < 8; ++j) p0 += qf[j] * b2f(k0[j]);
    p0 += __shfl_xor(p0, 1);
    p0 += __shfl_xor(p0, 2);
    p0 += __shfl_xor(p0, 4);
    if (!(lane & 7)) sc[(size_t)i * 8 + (lane >> 3)] = p0 * 0.125f;
  }
}

// ==================== global softmax over edge axis (per head) ==============
template<int OP>   // 0 = max, 1 = sum
__device__ __forceinline__ void reduce8_block(float (&v)[8], float* red) {
  int lane = threadIdx.x & 63, wid = threadIdx.x >> 6;
  #pragma unroll
  for (int h = 0; h < 8; ++h)
    #pragma unroll
    for (int off = 1; off < 64; off <<= 1) {
      float o = __shfl_xor(v[h], off);
      v[h] = OP ? (v[h] + o) : fmaxf(v[h], o);
    }
  if (lane == 0) {
    #pragma unroll
    for (int h = 0; h < 8; ++h) red[h * 4 + wid] = v[h];
  }
  __syncthreads();
  if (threadIdx.x == 0) {
    #pragma unroll
    for (int h = 0; h < 8; ++h) {
      float r = red[h * 4];
      #pragma unroll
      for (int w = 1; w < 4; ++w)
        r = OP ? (r + red[h * 4 + w]) : fmaxf(r, red[h * 4 + w]);
      v[h] = r;
    }
  }
}

__global__ __launch_bounds__(256) void sm_max_partial_kernel(
    const float* __restrict__ sc, int E, float* __restrict__ part)
{
  __shared__ float red[32];
  float v[8];
  #pragma unroll
  for (int h = 0; h < 8; ++h) v[h] = -1e30f;
  int stride = gridDim.x * 256;
  for (int e = blockIdx.x * 256 + threadIdx.x; e < E; e += stride) {
    #pragma unroll
    for (int h = 0; h < 8; ++h) v[h] = fmaxf(v[h], sc[(size_t)e * 8 + h]);
  }
  reduce8_block<0>(v, red);
  if (threadIdx.x == 0) {
    #pragma unroll
    for (int h = 0; h < 8; ++h) part[blockIdx.x * 8 + h] = v[h];
  }
}

__global__ __launch_bounds__(256) void sm_exp_partial_kernel(
    float* __restrict__ sc, int E, const float* __restrict__ partm,
    float* __restrict__ parts)
{
  __shared__ float red[32];
  __shared__ float gmx[8];
  float v[8];
  #pragma unroll
  for (int h = 0; h < 8; ++h) v[h] = partm[threadIdx.x * 8 + h];
  reduce8_block<0>(v, red);
  if (threadIdx.x == 0) {
    #pragma unroll
    for (int h = 0; h < 8; ++h) gmx[h] = v[h];
  }
  __syncthreads();
  float gm[8];
  #pragma unroll
  for (int h = 0; h < 8; ++h) { gm[h] = gmx[h]; v[h] = 0.f; }
  int stride = gridDim.x * 256;
  for (int e = blockIdx.x * 256 + threadIdx.x; e < E; e += stride) {
    #pragma unroll
    for (int h = 0; h < 8; ++h) {
      float w = __expf(sc[(size_t)e * 8 + h] - gm[h]);
      sc[(size_t)e * 8 + h] = w;           // in-place exp
      v[h] += w;
    }
  }
  reduce8_block<1>(v, red);
  if (threadIdx.x == 0) {
    #pragma unroll
    for (int h = 0; h < 8; ++h) parts[blockIdx.x * 8 + h] = v[h];
  }
}

template<int OP>   // 1: out = 1/sum
__global__ __launch_bounds__(256) void sm_final_kernel(
    const float* __restrict__ part, float* __restrict__ out)
{
  __shared__ float red[32];
  float v[8];
  #pragma unroll
  for (int h = 0; h < 8; ++h) v[h] = part[threadIdx.x * 8 + h];
  reduce8_block<OP>(v, red);
  if (threadIdx.x == 0) {
    #pragma unroll
    for (int h = 0; h < 8; ++h) out[h] = OP ? (1.0f / v[h]) : v[h];
  }
}

// =============================== CSR build ==================================
__global__ __launch_bounds__(256) void hist_kernel(
    const int* __restrict__ ei, int E, int* __restrict__ deg)
{
  int e = blockIdx.x * 256 + threadIdx.x;
  if (e < E) atomicAdd(&deg[ei[E + e]], 1);
}

__global__ __launch_bounds__(1024) void scan_part_kernel(
    const int* __restrict__ deg, int N, int* __restrict__ rowptr,
    int* __restrict__ bsums)
{
  __shared__ int wsum[16];
  int i = blockIdx.x * 1024 + threadIdx.x;
  int lane = threadIdx.x & 63, wid = threadIdx.x >> 6;
  int sv = (i < N) ? deg[i] : 0;
  #pragma unroll
  for (int off = 1; off < 64; off <<= 1) {
    int t = __shfl_up(sv, off);
    if (lane >= off) sv += t;
  }
  if (lane == 63) wsum[wid] = sv;
  __syncthreads();
  if (threadIdx.x < 16) {
    int ws = wsum[threadIdx.x];
    #pragma unroll
    for (int off = 1; off < 16; off <<= 1) {
      int t = __shfl_up(ws, off);
      if (threadIdx.x >= off) ws += t;
    }
    wsum[threadIdx.x] = ws;
  }
  __syncthreads();
  if (wid > 0) sv += wsum[wid - 1];
  if (i < N) rowptr[i + 1] = sv;
  if (threadIdx.x == 1023) bsums[blockIdx.x] = sv;
}

__global__ __launch_bounds__(64) void scan_bsums_kernel(int* bsums, int nb)
{
  int lane = threadIdx.x;
  int v = (lane < nb) ? bsums[lane] : 0;
  #pragma unroll
  for (int off = 1; off < 64; off <<= 1) {
    int t = __shfl_up(v, off);
    if (lane >= off) v += t;
  }
  int ex = __shfl_up(v, 1);
  if (lane == 0) ex = 0;
  if (lane < nb) bsums[lane] = ex;     // exclusive offsets, in place
}

__global__ __launch_bounds__(1024) void scan_add_kernel(
    int* __restrict__ rowptr, const int* __restrict__ bsums, int N)
{
  int i = blockIdx.x * 1024 + threadIdx.x;
  if (i == 0) rowptr[0] = 0;
  if (i < N && blockIdx.x > 0) rowptr[i + 1] += bsums[blockIdx.x];
}

__global__ __launch_bounds__(256) void scatter_kernel(
    const int* __restrict__ ei, int E, const int* __restrict__ rowptr,
    int* __restrict__ cur, int* __restrict__ srcs)
{
  int e = blockIdx.x * 256 + threadIdx.x;
  if (e < E) {
    int dst = ei[E + e];
    int pos = atomicAdd(&cur[dst], 1);
    srcs[rowptr[dst] + pos] = ei[e];
  }
}

// ====== aggregate: agg[n] = sum_{i in CSR(n)} w[i,h] * v[srcs[i]] ==========
__global__ __launch_bounds__(256) void aggregate_kernel(
    const unsigned short* __restrict__ qkv, const float* __restrict__ wexp,
    const float* __restrict__ ginv, const int* __restrict__ srcs,
    const int* __restrict__ rowptr, int N, unsigned short* __restrict__ agg)
{
  int wid = threadIdx.x >> 6, lane = threadIdx.x & 63;
  int n = (blockIdx.x << 2) | wid;
  if (n >= N) return;
  int beg = rowptr[n], end = rowptr[n + 1];
  int h = lane >> 3;
  float inv = ginv[h];
  float acc[8] = {0.f,0.f,0.f,0.f,0.f,0.f,0.f,0.f};
  int i = beg;
  for (; i + 2 <= end; i += 2) {       // 2-edge ILP
    int s0 = srcs[i], s1 = srcs[i + 1];
    float w0 = wexp[(size_t)i * 8 + h] * inv;
    float w1 = wexp[(size_t)(i + 1) * 8 + h] * inv;
    ushort8v v0 = *(const ushort8v*)(qkv + (size_t)s0 * 1536 + 1024 + (lane << 3));
    ushort8v v1 = *(const ushort8v*)(qkv + (size_t)s1 * 1536 + 1024 + (lane << 3));
    #pragma unroll
    for (int j = 0; j < 8; ++j) acc[j] += w0 * b2f(v0[j]) + w1 * b2f(v1[j]);
  }
  if (i < end) {
    int s0 = srcs[i];
    float w0 = wexp[(size_t)i * 8 + h] * inv;
    ushort8v v0 = *(const ushort8v*)(qkv + (size_t)s0 * 1536 + 1024 + (lane << 3));
    #pragma unroll
    for (int j = 0; j < 8; ++j) acc[j] += w0 * b2f(v0[j]);
  }
  ushort8v o;
  #pragma unroll
  for (int j = 0; j < 8; ++j) o[j] = f2b(acc[j]);
  *(ushort8v*)(agg + (size_t)n * 512 + (lane << 3)) = o;
}

// ====================== LN(proj + resid)*g + bt  (wave/row) =================
__global__ __launch_bounds__(256) void ln_kernel(
    const unsigned short* __restrict__ proj, const float* __restrict__ g,
    const float* __restrict__ bt, float* __restrict__ x,
    unsigned short* __restrict__ xb, int N)
{
  int wid = threadIdx.x >> 6, lane = threadIdx.x & 63;
  int n = (blockIdx.x << 2) | wid;
  if (n >= N) return;
  size_t base = (size_t)n * 512 + (lane << 3);
  ushort8v pv = *(const ushort8v*)(proj + base);
  const float4* xp = (const float4*)(x + base);
  float4 x0 = xp[0], x1 = xp[1];
  float y[8] = {b2f(pv[0]) + x0.x, b2f(pv[1]) + x0.y, b2f(pv[2]) + x0.z,
                b2f(pv[3]) + x0.w, b2f(pv[4]) + x1.x, b2f(pv[5]) + x1.y,
                b2f(pv[6]) + x1.z, b2f(pv[7]) + x1.w};
  float s = 0.f;
  #pragma unroll
  for (int j = 0; j < 8; ++j) s += y[j];
  #pragma unroll
  for (int off = 1; off < 64; off <<= 1) s += __shfl_xor(s, off);
  float mean = s * (1.f / 512.f);
  float vs = 0.f;
  #pragma unroll
  for (int j = 0; j < 8; ++j) { float d = y[j] - mean; vs += d * d; }
  #pragma unroll
  for (int off = 1; off < 64; off <<= 1) vs += __shfl_xor(vs, off);
  float rstd = rsqrtf(vs * (1.f / 512.f) + 1e-5f);
  int gi = lane << 3;
  float o[8];
  #pragma unroll
  for (int j = 0; j < 8; ++j) o[j] = (y[j] - mean) * rstd * g[gi + j] + bt[gi + j];
  float4 r0 = {o[0], o[1], o[2], o[3]}, r1 = {o[4], o[5], o[6], o[7]};
  *(float4*)(x + base) = r0;
  *(float4*)(x + base + 4) = r1;
  ushort8v ob;
  #pragma unroll
  for (int j = 0; j < 8; ++j) ob[j] = f2b(o[j]);
  *(ushort8v*)(xb + base) = ob;
}

// ================================ driver ====================================
extern "C" void kernel_launch(void* const* d_in, const int* in_sizes, int n_in,
                              void* d_out, int out_size, void* d_ws, size_t ws_size,
                              hipStream_t stream)
{
  (void)n_in; (void)out_size;
  const float* feat[3] = {(const float*)d_in[0], (const float*)d_in[1], (const float*)d_in[2]};
  const float* emb[3]  = {(const float*)d_in[3], (const float*)d_in[4], (const float*)d_in[5]};
  const float* pos[3]  = {(const float*)d_in[6], (const float*)d_in[7], (const float*)d_in[8]};
  const float* W[3]  = {(const float*)d_in[9],  (const float*)d_in[13], (const float*)d_in[17]};
  const float* Bb[3] = {(const float*)d_in[10], (const float*)d_in[14], (const float*)d_in[18]};
  const float* G[3]  = {(const float*)d_in[11], (const float*)d_in[15], (const float*)d_in[19]};
  const float* Bt[3] = {(const float*)d_in[12], (const float*)d_in[16], (const float*)d_in[20]};
  const float* headW = (const float*)d_in[21];
  const float* headB = (const float*)d_in[22];
  const int* ei[3] = {(const int*)d_in[23], (const int*)d_in[24], (const int*)d_in[25]};

  int Ns[3], Es[3];
  for (int s = 0; s < 3; ++s) { Ns[s] = in_sizes[s] / 512; Es[s] = in_sizes[23 + s] / 2; }
  int NMAX = Ns[0], EMAX = Es[0];
  for (int s = 1; s < 3; ++s) { if (Ns[s] > NMAX) NMAX = Ns[s]; if (Es[s] > EMAX) EMAX = Es[s]; }

  char* base = (char*)d_ws;
  size_t off = 0;
  auto carve = [&](size_t bytes) -> char* {
    char* r = base + off;
    off += (bytes + 255) & ~(size_t)255;
    return r;
  };
  unsigned short* WT  = (unsigned short*)carve((size_t)27 * 262144 * 2);
  float*          X   = (float*)carve((size_t)NMAX * 512 * 4);
  unsigned short* XB  = (unsigned short*)carve((size_t)NMAX * 512 * 2);
  unsigned short* QKV = (unsigned short*)carve((size_t)NMAX * 1536 * 2);
  float*          SC  = (float*)carve((size_t)EMAX * 8 * 4);
  unsigned short* AGG = (unsigned short*)carve((size_t)NMAX * 512 * 2);
  int*   ROWPTR = (int*)carve((size_t)(NMAX + 1) * 4);
  int*   DEG    = (int*)carve((size_t)NMAX * 4);
  int*   SRCS   = (int*)carve((size_t)EMAX * 4);
  int*   BSUMS  = (int*)carve(64 * 4);
  float* PARTM  = (float*)carve(256 * 8 * 4);
  float* PARTS  = (float*)carve(256 * 8 * 4);
  float* GINV   = (float*)carve(256);
  unsigned short* PROJ = QKV;    // alias: q/k/v slots dead once aggregate done
  if (off > ws_size) return;     // insufficient workspace: fail loudly

  // weights -> bf16 transposed + column-permuted ("WTs" layout for the GEMM)
  transpose_w_kernel<<<dim3(16,16,8), dim3(32,8), 0, stream>>>(W[0], WT);
  transpose_w_kernel<<<dim3(16,16,8), dim3(32,8), 0, stream>>>(W[1], WT + (size_t)8 * 262144);
  transpose_w_kernel<<<dim3(16,16,8), dim3(32,8), 0, stream>>>(W[2], WT + (size_t)16 * 262144);
  transpose_w_kernel<<<dim3(16,16,3), dim3(32,8), 0, stream>>>(headW, WT + (size_t)24 * 262144);

  size_t out_off = 0;
  for (int s = 0; s < 3; ++s) {
    const int N = Ns[s], E = Es[s];
    const int mt = (N + 255) >> 8;           // 256-row tiles
    const int nb = (N + 1023) / 1024;

    init_x_kernel<<<2048, 256, 0, stream>>>(
        (const float4*)feat[s], (const float4*)emb[s], (const float4*)pos[s],
        (float4*)X, XB, (long long)N * 128);

    // CSR by dst (edge index is constant per stream; built once, used 2x)
    hipMemsetAsync(DEG, 0, (size_t)N * 4, stream);
    hist_kernel<<<(E + 255) / 256, 256, 0, stream>>>(ei[s], E, DEG);
    scan_part_kernel<<<nb, 1024, 0, stream>>>(DEG, N, ROWPTR, BSUMS);
    scan_bsums_kernel<<<1, 64, 0, stream>>>(BSUMS, nb);
    scan_add_kernel<<<nb, 1024, 0, stream>>>(ROWPTR, BSUMS, N);
    hipMemsetAsync(DEG, 0, (size_t)N * 4, stream);
    scatter_kernel<<<(E + 255) / 256, 256, 0, stream>>>(ei[s], E, ROWPTR, DEG, SRCS);

    for (int l = 0; l < 2; ++l) {
      const unsigned short* Wqkv = WT + (size_t)(s * 8 + l * 4) * 262144;
      const unsigned short* Wo   = WT + (size_t)(s * 8 + l * 4 + 3) * 262144;
      const float* bqkv = Bb[s] + (size_t)l * 4 * 512;       // q,k,v biases contiguous
      const float* bo   = Bb[s] + (size_t)(l * 4 + 3) * 512;

      gemm_bt_kernel<1><<<dim3(mt * 6), 512, 0, stream>>>(XB, Wqkv, bqkv, QKV, N, 1536);
      csr_scores_kernel<<<(N + 3) / 4, 256, 0, stream>>>(QKV, SRCS, ROWPTR, N, SC);
      sm_max_partial_kernel<<<256, 256, 0, stream>>>(SC, E, PARTM);
      sm_exp_partial_kernel<<<256, 256, 0, stream>>>(SC, E, PARTM, PARTS);
      sm_final_kernel<1><<<1, 256, 0, stream>>>(PARTS, GINV);
      aggregate_kernel<<<(N + 3) / 4, 256, 0, stream>>>(QKV, SC, GINV, SRCS, ROWPTR, N, AGG);
      gemm_bt_kernel<1><<<dim3(mt * 2), 512, 0, stream>>>(AGG, Wo, bo, PROJ, N, 512);
      ln_kernel<<<(N + 3) / 4, 256, 0, stream>>>(PROJ, G[s] + (size_t)l * 512,
                                                 Bt[s] + (size_t)l * 512, X, XB, N);
    }

    gemm_bt_kernel<0><<<dim3(mt * 2), 512, 0, stream>>>(
        XB, WT + (size_t)(24 + s) * 262144, headB + (size_t)s * 512,
        (float*)d_out + out_off, N, 512);
    out_off += (size_t)N * 512;
  }
}